// Round 14
// baseline (271.344 us; speedup 1.0000x reference)
//
#include <hip/hip_runtime.h>
#include <hip/hip_bf16.h>
#include <math.h>

#define NE 80000
#define NN 10000
#define NG 16
#define NBLK 157   // ceil(NN/64)
#define MP_NORM 0.31622776601683794f   // 1/sqrt(10)
#define RBF_NORM 0.60302268915552724f  // sqrt(2/5.5)

// monomial tables: index -> (lx,ly,lz), l
__constant__ int c_mx[20] = {0, 1,0,0, 2,1,1,0,0,0, 3,2,2,1,1,1,0,0,0,0};
__constant__ int c_my[20] = {0, 0,1,0, 0,1,0,2,1,0, 0,1,0,2,1,0,3,2,1,0};
__constant__ int c_mz[20] = {0, 0,0,1, 0,0,1,0,1,2, 0,0,1,0,1,2,0,1,2,3};

__device__ __forceinline__ int l_of_a(int a) {
    return (a >= 10) ? 3 : ((a >= 4) ? 2 : ((a >= 1) ? 1 : 0));
}

// symmetrize one node's 1080-vector (in LDS, layout [s][a*9+c]) -> 324
__device__ __forceinline__ void symm_from_lds(const float* Als, float* brow,
                                              int lane) {
    if (lane >= 54) return;
    const int s2 = lane / 9, c = lane - s2 * 9;
    const float* a = Als + s2 * 180 + c;
    float v[20];
    #pragma unroll
    for (int i = 0; i < 20; i++) v[i] = a[i * 9];
    const float o0 = v[0];
    const float o1 = v[1]*v[1] + v[2]*v[2] + v[3]*v[3];
    const float o2 = v[4]*v[4] + 2.f*v[5]*v[5] + 2.f*v[6]*v[6]
                   + v[7]*v[7] + 2.f*v[8]*v[8] + v[9]*v[9];
    const float o3 = v[10]*v[10] + 3.f*v[11]*v[11] + 3.f*v[12]*v[12]
                   + 3.f*v[13]*v[13] + 6.f*v[14]*v[14] + 3.f*v[15]*v[15]
                   + v[16]*v[16] + 3.f*v[17]*v[17] + 3.f*v[18]*v[18] + v[19]*v[19];
    const float o4 = v[1]*v[1]*v[4] + 2.f*v[1]*v[2]*v[5] + 2.f*v[1]*v[3]*v[6]
                   + 2.f*v[2]*v[1]*v[5] + v[2]*v[2]*v[7] + 2.f*v[2]*v[3]*v[8]
                   + 2.f*v[3]*v[1]*v[6] + 2.f*v[3]*v[2]*v[8] + v[3]*v[3]*v[9];
    const float o5 =
        v[1]*(v[4]*v[10] + 3.f*v[5]*v[11] + 3.f*v[6]*v[12] + 3.f*v[7]*v[13]
              + 6.f*v[8]*v[14] + 3.f*v[9]*v[15])
      + v[2]*(3.f*v[4]*v[11] + 3.f*v[5]*v[13] + 6.f*v[6]*v[14] + v[7]*v[16]
              + 3.f*v[8]*v[17] + 3.f*v[9]*v[18])
      + v[3]*(3.f*v[4]*v[12] + 6.f*v[5]*v[14] + 3.f*v[6]*v[15] + 3.f*v[7]*v[17]
              + 3.f*v[8]*v[18] + v[9]*v[19]);
    float* b = brow + s2 * 54 + c;
    b[0]  = o0;
    b[9]  = o1;
    b[18] = o2;
    b[27] = o3;
    b[36] = o4;
    b[45] = o5;
}

// ---------------------------------------------------------------------------
// CSR build: histogram, scan, fill (fill precomputes per-active-edge
// geometry, source node, and 9-element edge code).
// ---------------------------------------------------------------------------
__global__ __launch_bounds__(256) void k_hist(
    const float* __restrict__ pos, const int* __restrict__ src,
    const int* __restrict__ dst, const float* __restrict__ shifts,
    int* __restrict__ indeg)
{
    const int e = blockIdx.x * 256 + threadIdx.x;
    if (e >= NE) return;
    const int sn = src[e], dn = dst[e];
    const float vx = pos[3*dn+0] - pos[3*sn+0] + shifts[3*e+0];
    const float vy = pos[3*dn+1] - pos[3*sn+1] + shifts[3*e+1];
    const float vz = pos[3*dn+2] - pos[3*sn+2] + shifts[3*e+2];
    const float r = sqrtf(vx*vx + vy*vy + vz*vz) + 1e-9f;
    if (r * (1.0f / 5.5f) < 1.0f) atomicAdd(&indeg[dn], 1);
}

__global__ __launch_bounds__(256) void k_scan(const int* __restrict__ indeg,
                                              int* __restrict__ offs)
{
    __shared__ int part[256];
    const int t = threadIdx.x;
    int s = 0;
    for (int i = t * 40; i < t * 40 + 40; i++)
        if (i < NN) s += indeg[i];
    part[t] = s;
    __syncthreads();
    if (t == 0) {
        int run = 0;
        for (int i = 0; i < 256; i++) { int v = part[i]; part[i] = run; run += v; }
    }
    __syncthreads();
    int run = part[t];
    for (int i = t * 40; i < t * 40 + 40; i++) {
        if (i < NN) { offs[i] = run; run += indeg[i]; }
    }
}

__global__ __launch_bounds__(256) void k_fill(
    const float* __restrict__ pos, const int* __restrict__ src,
    const int* __restrict__ dst, const float* __restrict__ shifts,
    const int* __restrict__ ntype, const float* __restrict__ Wemb,
    const int* __restrict__ offs, int* __restrict__ cursor,
    int* __restrict__ esrc, float4* __restrict__ egeo,
    float* __restrict__ ecode)
{
    const int e = blockIdx.x * 256 + threadIdx.x;
    if (e >= NE) return;
    const int sn = src[e], dn = dst[e];
    const float vx = pos[3*dn+0] - pos[3*sn+0] + shifts[3*e+0];
    const float vy = pos[3*dn+1] - pos[3*sn+1] + shifts[3*e+1];
    const float vz = pos[3*dn+2] - pos[3*sn+2] + shifts[3*e+2];
    const float r = sqrtf(vx*vx + vy*vy + vz*vz) + 1e-9f;
    if (r * (1.0f / 5.5f) < 1.0f) {
        const int p = offs[dn] + atomicAdd(&cursor[dn], 1);
        esrc[p] = sn;
        const float inv = 1.0f / r;
        egeo[p] = make_float4(vx*inv, vy*inv, vz*inv, r);
        const int ts = ntype[sn], td = ntype[dn];
        const float es0 = Wemb[3*ts], es1 = Wemb[3*ts+1], es2 = Wemb[3*ts+2];
        const float ed0 = Wemb[3*td], ed1 = Wemb[3*td+1], ed2 = Wemb[3*td+2];
        float* cp = ecode + (size_t)p * 9;
        cp[0] = es0*ed0; cp[1] = es0*ed1; cp[2] = es0*ed2;
        cp[3] = es1*ed0; cp[4] = es1*ed1; cp[5] = es1*ed2;
        cp[6] = es2*ed0; cp[7] = es2*ed1; cp[8] = es2*ed2;
    }
}

// per-edge angular/radial -> regX (and regY for node2's radA)
#define EDGE_REGX(g, ec)                                                       \
    float regX = (ec);                                                         \
    if (lane < 20) {                                                           \
        float v = 1.f;                                                         \
        for (int i = 0; i < mlx; i++) v *= (g).x;                              \
        for (int i = 0; i < mly; i++) v *= (g).y;                              \
        for (int i = 0; i < mlz; i++) v *= (g).z;                              \
        regX = v;                                                              \
    } else if (lane >= 29 && lane < 53) {                                      \
        const float r = (g).w;                                                 \
        const float u = r * (1.0f / 5.5f);                                     \
        const float u2 = u*u, u3 = u2*u, u6 = u3*u3;                           \
        const float fcv = 1.0f - 28.0f*u6 + 48.0f*u6*u - 21.0f*u6*u2;          \
        const float inv = fcv / r;                                             \
        float s = 0.f;                                                         \
        _Pragma("unroll")                                                      \
        for (int q = 0; q < 6; q++)                                            \
            s += RBF_NORM * __sinf(r * fr[q]) * inv * wrt[q];                  \
        regX = s;                                                              \
    }

// ---------------------------------------------------------------------------
// Pass 1: one wave/node, depth-2 pipelined edge loop (even/odd slots).
// Epilogue: A write, symmetrize -> Bls, pipelined chi, depth-3 GEMV -> P1.
// ---------------------------------------------------------------------------
__global__ __launch_bounds__(64) void k_node1(
    const float* __restrict__ freqs, const float* __restrict__ W_rt,
    const int* __restrict__ offs, const int* __restrict__ indeg,
    const int* __restrict__ esrc, const float4* __restrict__ egeo,
    const float* __restrict__ ecode, const float* __restrict__ W1,
    const float* __restrict__ W_chi,
    float* __restrict__ A, float* __restrict__ chi, float* __restrict__ P1)
{
    __shared__ float Als[1080];
    __shared__ float Bls[324];
    const int n = blockIdx.x, lane = threadIdx.x;
    int aslot[3], cslot[3], rslot[3];
    float acc[3][6];
    #pragma unroll
    for (int j = 0; j < 3; j++) {
        const int p = lane + 64 * j;
        const int pc = (p < 180) ? p : 0;
        aslot[j] = pc / 9;
        cslot[j] = 20 + pc % 9;
        rslot[j] = 29 + 6 * l_of_a(pc / 9);
        #pragma unroll
        for (int s = 0; s < 6; s++) acc[j][s] = 0.f;
    }
    float fr[6];
    #pragma unroll
    for (int q = 0; q < 6; q++) fr[q] = freqs[q];
    float wrt[6];
    if (lane >= 29 && lane < 53) {
        const int j = lane - 29, l = j / 6, s2 = j % 6;
        #pragma unroll
        for (int q = 0; q < 6; q++) wrt[q] = W_rt[(l*6 + q)*6 + s2];
    }
    int mlx = 0, mly = 0, mlz = 0;
    if (lane < 20) { mlx = c_mx[lane]; mly = c_my[lane]; mlz = c_mz[lane]; }
    const int e0 = offs[n], cnt = indeg[n];
    float4 geo0 = make_float4(0.f,0.f,0.f,1.f), geo1 = geo0;
    float ecd0 = 0.f, ecd1 = 0.f;
    if (cnt > 0) {
        geo0 = egeo[e0];
        if (lane >= 20 && lane < 29) ecd0 = ecode[(size_t)e0*9 + lane - 20];
    }
    if (cnt > 1) {
        geo1 = egeo[e0 + 1];
        if (lane >= 20 && lane < 29) ecd1 = ecode[(size_t)(e0+1)*9 + lane - 20];
    }
    for (int t = 0; t < cnt; t += 2) {
        {   // even edge t (slot 0)
            EDGE_REGX(geo0, ecd0)
            float pp[3];
            #pragma unroll
            for (int j = 0; j < 3; j++)
                pp[j] = __shfl(regX, aslot[j]) * __shfl(regX, cslot[j]);
            #pragma unroll
            for (int j = 0; j < 3; j++)
                #pragma unroll
                for (int s = 0; s < 6; s++)
                    acc[j][s] = fmaf(__shfl(regX, rslot[j] + s), pp[j],
                                     acc[j][s]);
            if (t + 2 < cnt) {
                geo0 = egeo[e0 + t + 2];
                if (lane >= 20 && lane < 29)
                    ecd0 = ecode[(size_t)(e0 + t + 2)*9 + lane - 20];
            }
        }
        if (t + 1 < cnt) {   // odd edge t+1 (slot 1)
            EDGE_REGX(geo1, ecd1)
            float pp[3];
            #pragma unroll
            for (int j = 0; j < 3; j++)
                pp[j] = __shfl(regX, aslot[j]) * __shfl(regX, cslot[j]);
            #pragma unroll
            for (int j = 0; j < 3; j++)
                #pragma unroll
                for (int s = 0; s < 6; s++)
                    acc[j][s] = fmaf(__shfl(regX, rslot[j] + s), pp[j],
                                     acc[j][s]);
            if (t + 3 < cnt) {
                geo1 = egeo[e0 + t + 3];
                if (lane >= 20 && lane < 29)
                    ecd1 = ecode[(size_t)(e0 + t + 3)*9 + lane - 20];
            }
        }
    }
    #pragma unroll
    for (int j = 0; j < 3; j++) {
        const int p = lane + 64 * j;
        if (p < 180) {
            #pragma unroll
            for (int s = 0; s < 6; s++) {
                A[(size_t)n*1080 + s*180 + p] = acc[j][s];
                Als[s*180 + p] = acc[j][s];
            }
        }
    }
    __syncthreads();
    symm_from_lds(Als, Bls, lane);
    __syncthreads();
    // pipelined chi: group g=lane/9 covers j in [47g, min(324,47g+47))
    {
        float s = 0.f;
        if (lane < 63) {
            const int cc = lane % 9, gg = lane / 9;
            const int jb = gg * 47;
            const int je = (jb + 47 < 324) ? (jb + 47) : 324;
            float wc = W_chi[jb * 9 + cc];
            for (int j = jb; j < je; j++) {
                const float wn = (j + 1 < je) ? W_chi[(j + 1) * 9 + cc] : 0.f;
                s = fmaf(Bls[j], wc, s);
                wc = wn;
            }
        }
        float tt;
        tt = __shfl(s, lane + 36); if (lane < 27) s += tt;
        tt = __shfl(s, lane + 18); if (lane < 18) s += tt;
        tt = __shfl(s, lane + 9);
        if (lane < 9) chi[(size_t)n * 9 + lane] = s + tt;
    }
    // depth-3 pipelined GEMV vs even W1 rows (324 = 18 x 18)
    {
        float c0[6], c1[6], c2[6];
        #pragma unroll
        for (int u = 0; u < 6; u++) {
            c0[u] = W1[(size_t)(2*(u     ))*64 + lane];
            c1[u] = W1[(size_t)(2*(u +  6))*64 + lane];
            c2[u] = W1[(size_t)(2*(u + 12))*64 + lane];
        }
        float s0=0.f, s1=0.f, s2=0.f, s3=0.f, s4=0.f, s5=0.f;
        for (int q = 0; q < 324; q += 18) {
            s0 = fmaf(Bls[q+0], c0[0], s0); s1 = fmaf(Bls[q+1], c0[1], s1);
            s2 = fmaf(Bls[q+2], c0[2], s2); s3 = fmaf(Bls[q+3], c0[3], s3);
            s4 = fmaf(Bls[q+4], c0[4], s4); s5 = fmaf(Bls[q+5], c0[5], s5);
            if (q + 18 < 324) {
                #pragma unroll
                for (int u = 0; u < 6; u++)
                    c0[u] = W1[(size_t)(2*(q + 18 + u))*64 + lane];
            }
            s0 = fmaf(Bls[q+6], c1[0], s0); s1 = fmaf(Bls[q+7], c1[1], s1);
            s2 = fmaf(Bls[q+8], c1[2], s2); s3 = fmaf(Bls[q+9], c1[3], s3);
            s4 = fmaf(Bls[q+10], c1[4], s4); s5 = fmaf(Bls[q+11], c1[5], s5);
            if (q + 24 < 324) {
                #pragma unroll
                for (int u = 0; u < 6; u++)
                    c1[u] = W1[(size_t)(2*(q + 24 + u))*64 + lane];
            }
            s0 = fmaf(Bls[q+12], c2[0], s0); s1 = fmaf(Bls[q+13], c2[1], s1);
            s2 = fmaf(Bls[q+14], c2[2], s2); s3 = fmaf(Bls[q+15], c2[3], s3);
            s4 = fmaf(Bls[q+16], c2[4], s4); s5 = fmaf(Bls[q+17], c2[5], s5);
            if (q + 30 < 324) {
                #pragma unroll
                for (int u = 0; u < 6; u++)
                    c2[u] = W1[(size_t)(2*(q + 30 + u))*64 + lane];
            }
        }
        P1[(size_t)n*64 + lane] = ((s0 + s1) + (s2 + s3)) + (s4 + s5);
    }
}

// ---------------------------------------------------------------------------
// Pass 2: one wave/node, depth-2 pipelined edge loop incl. A[src] rows and
// chi (even/odd slots; esrc prefetched 4 ahead). Epilogue: memory term,
// symmetrize, depth-3 GEMV vs odd W1 rows -> P2.
// ---------------------------------------------------------------------------
__global__ __launch_bounds__(64) void k_node2(
    const float* __restrict__ freqs, const float* __restrict__ W_rt,
    const float* __restrict__ W_Ar, const float* __restrict__ W_mem,
    const int* __restrict__ offs, const int* __restrict__ indeg,
    const int* __restrict__ esrc, const float4* __restrict__ egeo,
    const float* __restrict__ ecode, const float* __restrict__ chi,
    const float* __restrict__ A, const float* __restrict__ W1,
    float* __restrict__ P2)
{
    __shared__ float Als[1080];
    __shared__ float Qls[1080];
    __shared__ float Wm[144];
    __shared__ float B2ls[324];
    const int n = blockIdx.x, lane = threadIdx.x;
    #pragma unroll
    for (int k = 0; k < 17; k++) {
        const int i = lane + 64 * k;
        if (i < 1080) Als[i] = A[(size_t)n*1080 + i];
    }
    Wm[lane] = W_mem[lane];
    Wm[lane + 64] = W_mem[lane + 64];
    if (lane < 16) Wm[lane + 128] = W_mem[lane + 128];
    int aslot[3], cslot[3], rslot[3];
    float acc[3][6];
    #pragma unroll
    for (int j = 0; j < 3; j++) {
        const int p = lane + 64 * j;
        const int pc = (p < 180) ? p : 0;
        aslot[j] = pc / 9;
        cslot[j] = 20 + pc % 9;
        rslot[j] = 29 + 6 * l_of_a(pc / 9);
        #pragma unroll
        for (int s = 0; s < 6; s++) acc[j][s] = 0.f;
    }
    float fr[6];
    #pragma unroll
    for (int q = 0; q < 6; q++) fr[q] = freqs[q];
    float wrt[6], wrtA[6];
    if (lane >= 29 && lane < 53) {
        const int j = lane - 29, l = j / 6, s2 = j % 6;
        #pragma unroll
        for (int q = 0; q < 6; q++) {
            wrt[q]  = W_rt[(l*6 + q)*6 + s2];
            wrtA[q] = W_Ar[(l*6 + q)*6 + s2];
        }
    }
    int mlx = 0, mly = 0, mlz = 0;
    if (lane < 20) { mlx = c_mx[lane]; mly = c_my[lane]; mlz = c_mz[lane]; }
    __syncthreads();   // Als/Wm visible; loop below is barrier-free
    const int e0 = offs[n], cnt = indeg[n];
    float4 geo0 = make_float4(0.f,0.f,0.f,1.f), geo1 = geo0;
    float ecd0 = 0.f, ecd1 = 0.f, ch0 = 0.f, ch1 = 0.f;
    float an0[3][6], an1[3][6];
    #pragma unroll
    for (int j = 0; j < 3; j++)
        #pragma unroll
        for (int s = 0; s < 6; s++) { an0[j][s] = 0.f; an1[j][s] = 0.f; }
    if (cnt > 0) {
        const int sn = esrc[e0];
        geo0 = egeo[e0];
        if (lane >= 20 && lane < 29) {
            ecd0 = ecode[(size_t)e0*9 + lane - 20];
            ch0  = chi[(size_t)sn*9 + lane - 20];
        }
        const float* ar = A + (size_t)sn * 1080;
        #pragma unroll
        for (int j = 0; j < 3; j++)
            #pragma unroll
            for (int s = 0; s < 6; s++) an0[j][s] = ar[s*180 + lane + 64*j];
    }
    if (cnt > 1) {
        const int sn = esrc[e0 + 1];
        geo1 = egeo[e0 + 1];
        if (lane >= 20 && lane < 29) {
            ecd1 = ecode[(size_t)(e0+1)*9 + lane - 20];
            ch1  = chi[(size_t)sn*9 + lane - 20];
        }
        const float* ar = A + (size_t)sn * 1080;
        #pragma unroll
        for (int j = 0; j < 3; j++)
            #pragma unroll
            for (int s = 0; s < 6; s++) an1[j][s] = ar[s*180 + lane + 64*j];
    }
    int sE = (cnt > 2) ? esrc[e0 + 2] : 0;
    int sO = (cnt > 3) ? esrc[e0 + 3] : 0;
    for (int t = 0; t < cnt; t += 2) {
        {   // even edge t (slot 0)
            float regY = 0.f;
            EDGE_REGX(geo0, ecd0 * ch0)
            if (lane >= 29 && lane < 53) {
                const float r = geo0.w;
                const float u = r * (1.0f / 5.5f);
                const float u2 = u*u, u3 = u2*u, u6 = u3*u3;
                const float fcv = 1.0f - 28.0f*u6 + 48.0f*u6*u - 21.0f*u6*u2;
                const float inv = fcv / r;
                float sA = 0.f;
                #pragma unroll
                for (int q = 0; q < 6; q++)
                    sA = fmaf(RBF_NORM * __sinf(r * fr[q]) * inv, wrtA[q], sA);
                regY = sA;
            }
            float pp[3];
            #pragma unroll
            for (int j = 0; j < 3; j++)
                pp[j] = __shfl(regX, aslot[j]) * __shfl(regX, cslot[j]);
            #pragma unroll
            for (int j = 0; j < 3; j++)
                #pragma unroll
                for (int s = 0; s < 6; s++)
                    acc[j][s] += __shfl(regX, rslot[j] + s) * pp[j]
                               + an0[j][s] * __shfl(regY, rslot[j] + s);
            if (t + 2 < cnt) {
                geo0 = egeo[e0 + t + 2];
                if (lane >= 20 && lane < 29) {
                    ecd0 = ecode[(size_t)(e0 + t + 2)*9 + lane - 20];
                    ch0  = chi[(size_t)sE*9 + lane - 20];
                }
                const float* ar = A + (size_t)sE * 1080;
                #pragma unroll
                for (int j = 0; j < 3; j++)
                    #pragma unroll
                    for (int s = 0; s < 6; s++)
                        an0[j][s] = ar[s*180 + lane + 64*j];
                sE = (t + 4 < cnt) ? esrc[e0 + t + 4] : 0;
            }
        }
        if (t + 1 < cnt) {   // odd edge t+1 (slot 1)
            float regY = 0.f;
            EDGE_REGX(geo1, ecd1 * ch1)
            if (lane >= 29 && lane < 53) {
                const float r = geo1.w;
                const float u = r * (1.0f / 5.5f);
                const float u2 = u*u, u3 = u2*u, u6 = u3*u3;
                const float fcv = 1.0f - 28.0f*u6 + 48.0f*u6*u - 21.0f*u6*u2;
                const float inv = fcv / r;
                float sA = 0.f;
                #pragma unroll
                for (int q = 0; q < 6; q++)
                    sA = fmaf(RBF_NORM * __sinf(r * fr[q]) * inv, wrtA[q], sA);
                regY = sA;
            }
            float pp[3];
            #pragma unroll
            for (int j = 0; j < 3; j++)
                pp[j] = __shfl(regX, aslot[j]) * __shfl(regX, cslot[j]);
            #pragma unroll
            for (int j = 0; j < 3; j++)
                #pragma unroll
                for (int s = 0; s < 6; s++)
                    acc[j][s] += __shfl(regX, rslot[j] + s) * pp[j]
                               + an1[j][s] * __shfl(regY, rslot[j] + s);
            if (t + 3 < cnt) {
                geo1 = egeo[e0 + t + 3];
                if (lane >= 20 && lane < 29) {
                    ecd1 = ecode[(size_t)(e0 + t + 3)*9 + lane - 20];
                    ch1  = chi[(size_t)sO*9 + lane - 20];
                }
                const float* ar = A + (size_t)sO * 1080;
                #pragma unroll
                for (int j = 0; j < 3; j++)
                    #pragma unroll
                    for (int s = 0; s < 6; s++)
                        an1[j][s] = ar[s*180 + lane + 64*j];
                sO = (t + 5 < cnt) ? esrc[e0 + t + 5] : 0;
            }
        }
    }
    // memory term + MP_NORM -> Qls (Als reads hoisted per pair)
    #pragma unroll
    for (int j = 0; j < 3; j++) {
        const int p = lane + 64 * j;
        if (p < 180) {
            const int l = l_of_a(p / 9);
            float als6[6];
            #pragma unroll
            for (int sp = 0; sp < 6; sp++) als6[sp] = Als[sp*180 + p];
            #pragma unroll
            for (int s = 0; s < 6; s++) {
                float m = 0.f;
                #pragma unroll
                for (int sp = 0; sp < 6; sp++)
                    m = fmaf(als6[sp], Wm[l*36 + sp*6 + s], m);
                Qls[s*180 + p] = acc[j][s] * MP_NORM + m;
            }
        }
    }
    __syncthreads();
    symm_from_lds(Qls, B2ls, lane);
    __syncthreads();
    // depth-3 pipelined GEMV vs odd W1 rows
    {
        float c0[6], c1[6], c2[6];
        #pragma unroll
        for (int u = 0; u < 6; u++) {
            c0[u] = W1[(size_t)(2*(u     ) + 1)*64 + lane];
            c1[u] = W1[(size_t)(2*(u +  6) + 1)*64 + lane];
            c2[u] = W1[(size_t)(2*(u + 12) + 1)*64 + lane];
        }
        float s0=0.f, s1=0.f, s2=0.f, s3=0.f, s4=0.f, s5=0.f;
        for (int q = 0; q < 324; q += 18) {
            s0 = fmaf(B2ls[q+0], c0[0], s0); s1 = fmaf(B2ls[q+1], c0[1], s1);
            s2 = fmaf(B2ls[q+2], c0[2], s2); s3 = fmaf(B2ls[q+3], c0[3], s3);
            s4 = fmaf(B2ls[q+4], c0[4], s4); s5 = fmaf(B2ls[q+5], c0[5], s5);
            if (q + 18 < 324) {
                #pragma unroll
                for (int u = 0; u < 6; u++)
                    c0[u] = W1[(size_t)(2*(q + 18 + u) + 1)*64 + lane];
            }
            s0 = fmaf(B2ls[q+6], c1[0], s0); s1 = fmaf(B2ls[q+7], c1[1], s1);
            s2 = fmaf(B2ls[q+8], c1[2], s2); s3 = fmaf(B2ls[q+9], c1[3], s3);
            s4 = fmaf(B2ls[q+10], c1[4], s4); s5 = fmaf(B2ls[q+11], c1[5], s5);
            if (q + 24 < 324) {
                #pragma unroll
                for (int u = 0; u < 6; u++)
                    c1[u] = W1[(size_t)(2*(q + 24 + u) + 1)*64 + lane];
            }
            s0 = fmaf(B2ls[q+12], c2[0], s0); s1 = fmaf(B2ls[q+13], c2[1], s1);
            s2 = fmaf(B2ls[q+14], c2[2], s2); s3 = fmaf(B2ls[q+15], c2[3], s3);
            s4 = fmaf(B2ls[q+16], c2[4], s4); s5 = fmaf(B2ls[q+17], c2[5], s5);
            if (q + 30 < 324) {
                #pragma unroll
                for (int u = 0; u < 6; u++)
                    c2[u] = W1[(size_t)(2*(q + 30 + u) + 1)*64 + lane];
            }
        }
        P2[(size_t)n*64 + lane] = ((s0 + s1) + (s2 + s3)) + (s4 + s5);
    }
}

// ---------------------------------------------------------------------------
// Tail: 64 nodes per 256-thread block; LDS atomics only; block partials.
// ---------------------------------------------------------------------------
__global__ __launch_bounds__(256) void k_tail(
    const float* __restrict__ P1, const float* __restrict__ P2,
    const float* __restrict__ b1, const float* __restrict__ W2,
    const float* __restrict__ b2, const float* __restrict__ W3,
    const float* __restrict__ b3, const int* __restrict__ batch,
    float* __restrict__ part)
{
    __shared__ float h1s[64][66];
    __shared__ float W2L[2048];
    __shared__ float gsum[16];
    const int tid = threadIdx.x;
    const int nb = blockIdx.x * 64;
    if (tid < 16) gsum[tid] = 0.f;
    for (int idx = tid; idx < 2048; idx += 256) W2L[idx] = W2[idx];
    for (int idx = tid; idx < 4096; idx += 256) {
        const int nl = idx >> 6, o = idx & 63;
        float h = 0.f;
        if (nb + nl < NN)
            h = P1[(size_t)(nb + nl)*64 + o] + P2[(size_t)(nb + nl)*64 + o]
              + b1[o];
        h1s[nl][o] = h / (1.f + __expf(-h));
    }
    __syncthreads();
    const int nl = tid >> 2, og = (tid & 3) * 8;
    float acc2[8];
    #pragma unroll
    for (int j = 0; j < 8; j++) acc2[j] = b2[og + j];
    #pragma unroll 8
    for (int k = 0; k < 64; k++) {
        const float hv = h1s[nl][k];
        const float4 wA = *(const float4*)&W2L[k*32 + og];
        const float4 wB = *(const float4*)&W2L[k*32 + og + 4];
        acc2[0] = fmaf(hv, wA.x, acc2[0]); acc2[1] = fmaf(hv, wA.y, acc2[1]);
        acc2[2] = fmaf(hv, wA.z, acc2[2]); acc2[3] = fmaf(hv, wA.w, acc2[3]);
        acc2[4] = fmaf(hv, wB.x, acc2[4]); acc2[5] = fmaf(hv, wB.y, acc2[5]);
        acc2[6] = fmaf(hv, wB.z, acc2[6]); acc2[7] = fmaf(hv, wB.w, acc2[7]);
    }
    float s = 0.f;
    #pragma unroll
    for (int j = 0; j < 8; j++) {
        const float g = acc2[j] / (1.f + __expf(-acc2[j]));
        s = fmaf(g, W3[og + j], s);
    }
    s += __shfl_xor(s, 1);
    s += __shfl_xor(s, 2);
    if ((tid & 3) == 0 && nb + nl < NN)
        atomicAdd(&gsum[batch[nb + nl]], s + b3[0]);
    __syncthreads();
    if (tid < 16) part[blockIdx.x * 16 + tid] = gsum[tid];
}

__global__ __launch_bounds__(64) void k_final(const float* __restrict__ part,
                                              float* __restrict__ out)
{
    const int t = threadIdx.x;
    if (t >= 16) return;
    float acc = 0.f;
    for (int b = 0; b < NBLK; b++) acc += part[b * 16 + t];
    out[t] = acc;
}

extern "C" void kernel_launch(void* const* d_in, const int* in_sizes, int n_in,
                              void* d_out, int out_size, void* d_ws, size_t ws_size,
                              hipStream_t stream)
{
    const float* pos    = (const float*)d_in[0];
    const int*   ntype  = (const int*)  d_in[1];
    const int*   src    = (const int*)  d_in[2];
    const int*   dst    = (const int*)  d_in[3];
    const float* shifts = (const float*)d_in[4];
    const int*   batch  = (const int*)  d_in[5];
    const float* Wemb   = (const float*)d_in[6];
    const float* freqs  = (const float*)d_in[7];
    const float* W_rt   = (const float*)d_in[8];
    const float* W_mem  = (const float*)d_in[9];
    const float* W_Ar   = (const float*)d_in[10];
    const float* W_chi  = (const float*)d_in[11];
    const float* W1     = (const float*)d_in[12];
    const float* b1     = (const float*)d_in[13];
    const float* W2     = (const float*)d_in[14];
    const float* b2     = (const float*)d_in[15];
    const float* W3     = (const float*)d_in[16];
    const float* b3     = (const float*)d_in[17];

    float*  ws    = (float*)d_ws;
    float*  A     = ws;                        // [NN,1080]
    float*  P1    = A    + (size_t)NN * 1080;  // [NN,64]
    float*  P2    = P1   + (size_t)NN * 64;    // [NN,64]
    float*  chi   = P2   + (size_t)NN * 64;    // [NN,9]
    float4* egeo  = (float4*)(chi + (size_t)NN * 9);       // [NE]
    int*    esrc  = (int*)(egeo + NE);                     // [NE]
    float*  ecode = (float*)(esrc + NE);                   // [NE,9]
    float*  part  = ecode + (size_t)NE * 9;                // [NBLK,16]
    int*    indeg  = (int*)(part + NBLK * 16);
    int*    offs   = indeg  + 10240;
    int*    cursor = offs   + 10240;

    hipMemsetAsync(indeg,  0, 10240 * sizeof(int), stream);
    hipMemsetAsync(cursor, 0, 10240 * sizeof(int), stream);

    k_hist<<<(NE + 255)/256, 256, 0, stream>>>(pos, src, dst, shifts, indeg);
    k_scan<<<1, 256, 0, stream>>>(indeg, offs);
    k_fill<<<(NE + 255)/256, 256, 0, stream>>>(pos, src, dst, shifts, ntype,
                                               Wemb, offs, cursor, esrc, egeo,
                                               ecode);
    k_node1<<<NN, 64, 0, stream>>>(freqs, W_rt, offs, indeg, esrc, egeo, ecode,
                                   W1, W_chi, A, chi, P1);
    k_node2<<<NN, 64, 0, stream>>>(freqs, W_rt, W_Ar, W_mem, offs, indeg, esrc,
                                   egeo, ecode, chi, A, W1, P2);
    k_tail<<<NBLK, 256, 0, stream>>>(P1, P2, b1, W2, b2, W3, b3, batch, part);
    k_final<<<1, 64, 0, stream>>>(part, (float*)d_out);
}

// Round 15
// 198.811 us; speedup vs baseline: 1.3648x; 1.3648x over previous
//
#include <hip/hip_runtime.h>
#include <hip/hip_bf16.h>
#include <math.h>

#define NE 80000
#define NN 10000
#define NG 16
#define NBLK 157   // ceil(NN/64)
#define MP_NORM 0.31622776601683794f   // 1/sqrt(10)
#define RBF_NORM 0.60302268915552724f  // sqrt(2/5.5)

// monomial tables: index -> (lx,ly,lz), l
__constant__ int c_mx[20] = {0, 1,0,0, 2,1,1,0,0,0, 3,2,2,1,1,1,0,0,0,0};
__constant__ int c_my[20] = {0, 0,1,0, 0,1,0,2,1,0, 0,1,0,2,1,0,3,2,1,0};
__constant__ int c_mz[20] = {0, 0,0,1, 0,0,1,0,1,2, 0,0,1,0,1,2,0,1,2,3};

__device__ __forceinline__ int l_of_a(int a) {
    return (a >= 10) ? 3 : ((a >= 4) ? 2 : ((a >= 1) ? 1 : 0));
}

// symmetrize one node's 1080-vector (in LDS, layout [s][a*9+c]) -> 324
__device__ __forceinline__ void symm_from_lds(const float* Als, float* brow,
                                              int lane) {
    if (lane >= 54) return;
    const int s2 = lane / 9, c = lane - s2 * 9;
    const float* a = Als + s2 * 180 + c;
    float v[20];
    #pragma unroll
    for (int i = 0; i < 20; i++) v[i] = a[i * 9];
    const float o0 = v[0];
    const float o1 = v[1]*v[1] + v[2]*v[2] + v[3]*v[3];
    const float o2 = v[4]*v[4] + 2.f*v[5]*v[5] + 2.f*v[6]*v[6]
                   + v[7]*v[7] + 2.f*v[8]*v[8] + v[9]*v[9];
    const float o3 = v[10]*v[10] + 3.f*v[11]*v[11] + 3.f*v[12]*v[12]
                   + 3.f*v[13]*v[13] + 6.f*v[14]*v[14] + 3.f*v[15]*v[15]
                   + v[16]*v[16] + 3.f*v[17]*v[17] + 3.f*v[18]*v[18] + v[19]*v[19];
    const float o4 = v[1]*v[1]*v[4] + 2.f*v[1]*v[2]*v[5] + 2.f*v[1]*v[3]*v[6]
                   + 2.f*v[2]*v[1]*v[5] + v[2]*v[2]*v[7] + 2.f*v[2]*v[3]*v[8]
                   + 2.f*v[3]*v[1]*v[6] + 2.f*v[3]*v[2]*v[8] + v[3]*v[3]*v[9];
    const float o5 =
        v[1]*(v[4]*v[10] + 3.f*v[5]*v[11] + 3.f*v[6]*v[12] + 3.f*v[7]*v[13]
              + 6.f*v[8]*v[14] + 3.f*v[9]*v[15])
      + v[2]*(3.f*v[4]*v[11] + 3.f*v[5]*v[13] + 6.f*v[6]*v[14] + v[7]*v[16]
              + 3.f*v[8]*v[17] + 3.f*v[9]*v[18])
      + v[3]*(3.f*v[4]*v[12] + 6.f*v[5]*v[14] + 3.f*v[6]*v[15] + 3.f*v[7]*v[17]
              + 3.f*v[8]*v[18] + v[9]*v[19]);
    float* b = brow + s2 * 54 + c;
    b[0]  = o0;
    b[9]  = o1;
    b[18] = o2;
    b[27] = o3;
    b[36] = o4;
    b[45] = o5;
}

// ---------------------------------------------------------------------------
// CSR build: histogram, scan, fill (fill precomputes per-active-edge
// geometry, source node, and 9-element edge code).
// ---------------------------------------------------------------------------
__global__ __launch_bounds__(256) void k_hist(
    const float* __restrict__ pos, const int* __restrict__ src,
    const int* __restrict__ dst, const float* __restrict__ shifts,
    int* __restrict__ indeg)
{
    const int e = blockIdx.x * 256 + threadIdx.x;
    if (e >= NE) return;
    const int sn = src[e], dn = dst[e];
    const float vx = pos[3*dn+0] - pos[3*sn+0] + shifts[3*e+0];
    const float vy = pos[3*dn+1] - pos[3*sn+1] + shifts[3*e+1];
    const float vz = pos[3*dn+2] - pos[3*sn+2] + shifts[3*e+2];
    const float r = sqrtf(vx*vx + vy*vy + vz*vz) + 1e-9f;
    if (r * (1.0f / 5.5f) < 1.0f) atomicAdd(&indeg[dn], 1);
}

__global__ __launch_bounds__(256) void k_scan(const int* __restrict__ indeg,
                                              int* __restrict__ offs)
{
    __shared__ int part[256];
    const int t = threadIdx.x;
    int s = 0;
    for (int i = t * 40; i < t * 40 + 40; i++)
        if (i < NN) s += indeg[i];
    part[t] = s;
    __syncthreads();
    if (t == 0) {
        int run = 0;
        for (int i = 0; i < 256; i++) { int v = part[i]; part[i] = run; run += v; }
    }
    __syncthreads();
    int run = part[t];
    for (int i = t * 40; i < t * 40 + 40; i++) {
        if (i < NN) { offs[i] = run; run += indeg[i]; }
    }
}

__global__ __launch_bounds__(256) void k_fill(
    const float* __restrict__ pos, const int* __restrict__ src,
    const int* __restrict__ dst, const float* __restrict__ shifts,
    const int* __restrict__ ntype, const float* __restrict__ Wemb,
    const int* __restrict__ offs, int* __restrict__ cursor,
    int* __restrict__ esrc, float4* __restrict__ egeo,
    float* __restrict__ ecode)
{
    const int e = blockIdx.x * 256 + threadIdx.x;
    if (e >= NE) return;
    const int sn = src[e], dn = dst[e];
    const float vx = pos[3*dn+0] - pos[3*sn+0] + shifts[3*e+0];
    const float vy = pos[3*dn+1] - pos[3*sn+1] + shifts[3*e+1];
    const float vz = pos[3*dn+2] - pos[3*sn+2] + shifts[3*e+2];
    const float r = sqrtf(vx*vx + vy*vy + vz*vz) + 1e-9f;
    if (r * (1.0f / 5.5f) < 1.0f) {
        const int p = offs[dn] + atomicAdd(&cursor[dn], 1);
        esrc[p] = sn;
        const float inv = 1.0f / r;
        egeo[p] = make_float4(vx*inv, vy*inv, vz*inv, r);
        const int ts = ntype[sn], td = ntype[dn];
        const float es0 = Wemb[3*ts], es1 = Wemb[3*ts+1], es2 = Wemb[3*ts+2];
        const float ed0 = Wemb[3*td], ed1 = Wemb[3*td+1], ed2 = Wemb[3*td+2];
        float* cp = ecode + (size_t)p * 9;
        cp[0] = es0*ed0; cp[1] = es0*ed1; cp[2] = es0*ed2;
        cp[3] = es1*ed0; cp[4] = es1*ed1; cp[5] = es1*ed2;
        cp[6] = es2*ed0; cp[7] = es2*ed1; cp[8] = es2*ed2;
    }
}

// ---------------------------------------------------------------------------
// Pass 1: one wave/node, barrier-free edge loop, factored triple-product
// (r12 structure). Epilogue: A write, symmetrize -> Bls, pipelined chi,
// pipelined GEMV vs even W1 rows -> P1.
// ---------------------------------------------------------------------------
__global__ __launch_bounds__(64) void k_node1(
    const float* __restrict__ freqs, const float* __restrict__ W_rt,
    const int* __restrict__ offs, const int* __restrict__ indeg,
    const int* __restrict__ esrc, const float4* __restrict__ egeo,
    const float* __restrict__ ecode, const float* __restrict__ W1,
    const float* __restrict__ W_chi,
    float* __restrict__ A, float* __restrict__ chi, float* __restrict__ P1)
{
    __shared__ float Als[1080];
    __shared__ float Bls[324];
    const int n = blockIdx.x, lane = threadIdx.x;
    int aslot[3], cslot[3], rslot[3];
    float acc[3][6];
    #pragma unroll
    for (int j = 0; j < 3; j++) {
        const int p = lane + 64 * j;
        const int pc = (p < 180) ? p : 0;
        aslot[j] = pc / 9;
        cslot[j] = 20 + pc % 9;
        rslot[j] = 29 + 6 * l_of_a(pc / 9);
        #pragma unroll
        for (int s = 0; s < 6; s++) acc[j][s] = 0.f;
    }
    float fr[6];
    #pragma unroll
    for (int q = 0; q < 6; q++) fr[q] = freqs[q];
    float wrt[6];
    if (lane >= 29 && lane < 53) {
        const int j = lane - 29, l = j / 6, s2 = j % 6;
        #pragma unroll
        for (int q = 0; q < 6; q++) wrt[q] = W_rt[(l*6 + q)*6 + s2];
    }
    int mlx = 0, mly = 0, mlz = 0;
    if (lane < 20) { mlx = c_mx[lane]; mly = c_my[lane]; mlz = c_mz[lane]; }
    const int e0 = offs[n], cnt = indeg[n];
    float4 geo = make_float4(0.f, 0.f, 0.f, 1.f);
    float ecd = 0.f;
    if (cnt > 0) {
        geo = egeo[e0];
        if (lane >= 20 && lane < 29) ecd = ecode[(size_t)e0*9 + lane - 20];
    }
    for (int t = 0; t < cnt; t++) {
        const float4 g = geo;
        const float ec = ecd;
        if (t + 1 < cnt) {
            geo = egeo[e0 + t + 1];
            if (lane >= 20 && lane < 29)
                ecd = ecode[(size_t)(e0 + t + 1)*9 + lane - 20];
        }
        float regX = ec;
        if (lane < 20) {
            float v = 1.f;
            for (int i = 0; i < mlx; i++) v *= g.x;
            for (int i = 0; i < mly; i++) v *= g.y;
            for (int i = 0; i < mlz; i++) v *= g.z;
            regX = v;
        } else if (lane >= 29 && lane < 53) {
            const float r = g.w;
            const float u = r * (1.0f / 5.5f);
            const float u2 = u*u, u3 = u2*u, u6 = u3*u3;
            const float fcv = 1.0f - 28.0f*u6 + 48.0f*u6*u - 21.0f*u6*u2;
            const float inv = fcv / r;
            float s = 0.f;
            #pragma unroll
            for (int q = 0; q < 6; q++)
                s += RBF_NORM * __sinf(r * fr[q]) * inv * wrt[q];
            regX = s;
        }
        float pp[3];
        #pragma unroll
        for (int j = 0; j < 3; j++)
            pp[j] = __shfl(regX, aslot[j]) * __shfl(regX, cslot[j]);
        #pragma unroll
        for (int j = 0; j < 3; j++) {
            #pragma unroll
            for (int s = 0; s < 6; s++)
                acc[j][s] = fmaf(__shfl(regX, rslot[j] + s), pp[j], acc[j][s]);
        }
    }
    #pragma unroll
    for (int j = 0; j < 3; j++) {
        const int p = lane + 64 * j;
        if (p < 180) {
            #pragma unroll
            for (int s = 0; s < 6; s++) {
                A[(size_t)n*1080 + s*180 + p] = acc[j][s];
                Als[s*180 + p] = acc[j][s];
            }
        }
    }
    __syncthreads();
    symm_from_lds(Als, Bls, lane);
    __syncthreads();
    // pipelined chi: group g=lane/9 covers j in [47g, min(324,47g+47))
    {
        float s = 0.f;
        if (lane < 63) {
            const int cc = lane % 9, gg = lane / 9;
            const int jb = gg * 47;
            const int je = (jb + 47 < 324) ? (jb + 47) : 324;
            float wc = W_chi[jb * 9 + cc];
            for (int j = jb; j < je; j++) {
                const float wn = (j + 1 < je) ? W_chi[(j + 1) * 9 + cc] : 0.f;
                s = fmaf(Bls[j], wc, s);
                wc = wn;
            }
        }
        float tt;
        tt = __shfl(s, lane + 36); if (lane < 27) s += tt;
        tt = __shfl(s, lane + 18); if (lane < 18) s += tt;
        tt = __shfl(s, lane + 9);
        if (lane < 9) chi[(size_t)n * 9 + lane] = s + tt;
    }
    // pipelined GEMV vs even W1 rows (324 = 54 x 6)
    {
        float cur[6], nxt[6];
        #pragma unroll
        for (int u = 0; u < 6; u++) cur[u] = W1[(size_t)(2*u)*64 + lane];
        float s0=0.f, s1=0.f, s2=0.f, s3=0.f, s4=0.f, s5=0.f;
        for (int q = 0; q < 324; q += 6) {
            const int qn = q + 6;
            if (qn < 324) {
                #pragma unroll
                for (int u = 0; u < 6; u++)
                    nxt[u] = W1[(size_t)(2*(qn+u))*64 + lane];
            }
            s0 = fmaf(Bls[q+0], cur[0], s0);
            s1 = fmaf(Bls[q+1], cur[1], s1);
            s2 = fmaf(Bls[q+2], cur[2], s2);
            s3 = fmaf(Bls[q+3], cur[3], s3);
            s4 = fmaf(Bls[q+4], cur[4], s4);
            s5 = fmaf(Bls[q+5], cur[5], s5);
            #pragma unroll
            for (int u = 0; u < 6; u++) cur[u] = nxt[u];
        }
        P1[(size_t)n*64 + lane] = ((s0 + s1) + (s2 + s3)) + (s4 + s5);
    }
}

// ---------------------------------------------------------------------------
// Pass 2: r12 structure; Qls ELIMINATED (memory term computed in place on
// Als -- each lane owns its pairs, als6 hoisted to regs first). LDS 6.2 KB.
// ---------------------------------------------------------------------------
__global__ __launch_bounds__(64) void k_node2(
    const float* __restrict__ freqs, const float* __restrict__ W_rt,
    const float* __restrict__ W_Ar, const float* __restrict__ W_mem,
    const int* __restrict__ offs, const int* __restrict__ indeg,
    const int* __restrict__ esrc, const float4* __restrict__ egeo,
    const float* __restrict__ ecode, const float* __restrict__ chi,
    const float* __restrict__ A, const float* __restrict__ W1,
    float* __restrict__ P2)
{
    __shared__ float Als[1080];
    __shared__ float Wm[144];
    __shared__ float B2ls[324];
    const int n = blockIdx.x, lane = threadIdx.x;
    #pragma unroll
    for (int k = 0; k < 17; k++) {
        const int i = lane + 64 * k;
        if (i < 1080) Als[i] = A[(size_t)n*1080 + i];
    }
    Wm[lane] = W_mem[lane];
    Wm[lane + 64] = W_mem[lane + 64];
    if (lane < 16) Wm[lane + 128] = W_mem[lane + 128];
    int aslot[3], cslot[3], rslot[3];
    float acc[3][6];
    #pragma unroll
    for (int j = 0; j < 3; j++) {
        const int p = lane + 64 * j;
        const int pc = (p < 180) ? p : 0;
        aslot[j] = pc / 9;
        cslot[j] = 20 + pc % 9;
        rslot[j] = 29 + 6 * l_of_a(pc / 9);
        #pragma unroll
        for (int s = 0; s < 6; s++) acc[j][s] = 0.f;
    }
    float fr[6];
    #pragma unroll
    for (int q = 0; q < 6; q++) fr[q] = freqs[q];
    float wrtB[6], wrtA[6];
    if (lane >= 29 && lane < 53) {
        const int j = lane - 29, l = j / 6, s2 = j % 6;
        #pragma unroll
        for (int q = 0; q < 6; q++) {
            wrtB[q] = W_rt[(l*6 + q)*6 + s2];
            wrtA[q] = W_Ar[(l*6 + q)*6 + s2];
        }
    }
    int mlx = 0, mly = 0, mlz = 0;
    if (lane < 20) { mlx = c_mx[lane]; mly = c_my[lane]; mlz = c_mz[lane]; }
    __syncthreads();   // Als/Wm visible; loop below is barrier-free
    const int e0 = offs[n], cnt = indeg[n];
    int sn2 = 0;
    float4 geo = make_float4(0.f, 0.f, 0.f, 1.f);
    float ecd = 0.f, chin = 0.f;
    float an[3][6];
    #pragma unroll
    for (int j = 0; j < 3; j++)
        #pragma unroll
        for (int s = 0; s < 6; s++) an[j][s] = 0.f;
    if (cnt > 0) {
        const int sn1 = esrc[e0];
        geo = egeo[e0];
        if (lane >= 20 && lane < 29) {
            ecd  = ecode[(size_t)e0*9 + lane - 20];
            chin = chi[(size_t)sn1*9 + lane - 20];
        }
        const float* ar = A + (size_t)sn1 * 1080;
        #pragma unroll
        for (int j = 0; j < 3; j++)
            #pragma unroll
            for (int s = 0; s < 6; s++) an[j][s] = ar[s*180 + lane + 64*j];
    }
    if (cnt > 1) sn2 = esrc[e0 + 1];
    for (int t = 0; t < cnt; t++) {
        const float4 g = geo;
        const float ec = ecd, ch = chin;
        float av[3][6];
        #pragma unroll
        for (int j = 0; j < 3; j++)
            #pragma unroll
            for (int s = 0; s < 6; s++) av[j][s] = an[j][s];
        if (t + 1 < cnt) {
            geo = egeo[e0 + t + 1];
            if (lane >= 20 && lane < 29) {
                ecd  = ecode[(size_t)(e0 + t + 1)*9 + lane - 20];
                chin = chi[(size_t)sn2*9 + lane - 20];
            }
            const float* ar = A + (size_t)sn2 * 1080;
            #pragma unroll
            for (int j = 0; j < 3; j++)
                #pragma unroll
                for (int s = 0; s < 6; s++) an[j][s] = ar[s*180 + lane + 64*j];
            if (t + 2 < cnt) sn2 = esrc[e0 + t + 2];
        }
        float regX = ec * ch;
        float regY = 0.f;
        if (lane < 20) {
            float v = 1.f;
            for (int i = 0; i < mlx; i++) v *= g.x;
            for (int i = 0; i < mly; i++) v *= g.y;
            for (int i = 0; i < mlz; i++) v *= g.z;
            regX = v;
        } else if (lane >= 29 && lane < 53) {
            const float r = g.w;
            const float u = r * (1.0f / 5.5f);
            const float u2 = u*u, u3 = u2*u, u6 = u3*u3;
            const float fcv = 1.0f - 28.0f*u6 + 48.0f*u6*u - 21.0f*u6*u2;
            const float inv = fcv / r;
            float sB = 0.f, sA = 0.f;
            #pragma unroll
            for (int q = 0; q < 6; q++) {
                const float rb = RBF_NORM * __sinf(r * fr[q]) * inv;
                sB = fmaf(rb, wrtB[q], sB);
                sA = fmaf(rb, wrtA[q], sA);
            }
            regX = sB;
            regY = sA;
        }
        float pp[3];
        #pragma unroll
        for (int j = 0; j < 3; j++)
            pp[j] = __shfl(regX, aslot[j]) * __shfl(regX, cslot[j]);
        #pragma unroll
        for (int j = 0; j < 3; j++) {
            #pragma unroll
            for (int s = 0; s < 6; s++) {
                const float rB = __shfl(regX, rslot[j] + s);
                const float rA = __shfl(regY, rslot[j] + s);
                acc[j][s] += rB * pp[j] + av[j][s] * rA;
            }
        }
    }
    // memory term + MP_NORM, IN PLACE on Als (als6 hoisted; lane owns pair)
    #pragma unroll
    for (int j = 0; j < 3; j++) {
        const int p = lane + 64 * j;
        if (p < 180) {
            const int l = l_of_a(p / 9);
            float als6[6];
            #pragma unroll
            for (int sp = 0; sp < 6; sp++) als6[sp] = Als[sp*180 + p];
            #pragma unroll
            for (int s = 0; s < 6; s++) {
                float m = 0.f;
                #pragma unroll
                for (int sp = 0; sp < 6; sp++)
                    m = fmaf(als6[sp], Wm[l*36 + sp*6 + s], m);
                Als[s*180 + p] = acc[j][s] * MP_NORM + m;
            }
        }
    }
    __syncthreads();
    symm_from_lds(Als, B2ls, lane);
    __syncthreads();
    // pipelined GEMV vs odd W1 rows
    {
        float cur[6], nxt[6];
        #pragma unroll
        for (int u = 0; u < 6; u++) cur[u] = W1[(size_t)(2*u + 1)*64 + lane];
        float s0=0.f, s1=0.f, s2=0.f, s3=0.f, s4=0.f, s5=0.f;
        for (int q = 0; q < 324; q += 6) {
            const int qn = q + 6;
            if (qn < 324) {
                #pragma unroll
                for (int u = 0; u < 6; u++)
                    nxt[u] = W1[(size_t)(2*(qn+u) + 1)*64 + lane];
            }
            s0 = fmaf(B2ls[q+0], cur[0], s0);
            s1 = fmaf(B2ls[q+1], cur[1], s1);
            s2 = fmaf(B2ls[q+2], cur[2], s2);
            s3 = fmaf(B2ls[q+3], cur[3], s3);
            s4 = fmaf(B2ls[q+4], cur[4], s4);
            s5 = fmaf(B2ls[q+5], cur[5], s5);
            #pragma unroll
            for (int u = 0; u < 6; u++) cur[u] = nxt[u];
        }
        P2[(size_t)n*64 + lane] = ((s0 + s1) + (s2 + s3)) + (s4 + s5);
    }
}

// ---------------------------------------------------------------------------
// Tail: 64 nodes per 256-thread block; LDS atomics only; block partials.
// ---------------------------------------------------------------------------
__global__ __launch_bounds__(256) void k_tail(
    const float* __restrict__ P1, const float* __restrict__ P2,
    const float* __restrict__ b1, const float* __restrict__ W2,
    const float* __restrict__ b2, const float* __restrict__ W3,
    const float* __restrict__ b3, const int* __restrict__ batch,
    float* __restrict__ part)
{
    __shared__ float h1s[64][66];
    __shared__ float W2L[2048];
    __shared__ float gsum[16];
    const int tid = threadIdx.x;
    const int nb = blockIdx.x * 64;
    if (tid < 16) gsum[tid] = 0.f;
    for (int idx = tid; idx < 2048; idx += 256) W2L[idx] = W2[idx];
    for (int idx = tid; idx < 4096; idx += 256) {
        const int nl = idx >> 6, o = idx & 63;
        float h = 0.f;
        if (nb + nl < NN)
            h = P1[(size_t)(nb + nl)*64 + o] + P2[(size_t)(nb + nl)*64 + o]
              + b1[o];
        h1s[nl][o] = h / (1.f + __expf(-h));
    }
    __syncthreads();
    const int nl = tid >> 2, og = (tid & 3) * 8;
    float acc2[8];
    #pragma unroll
    for (int j = 0; j < 8; j++) acc2[j] = b2[og + j];
    #pragma unroll 8
    for (int k = 0; k < 64; k++) {
        const float hv = h1s[nl][k];
        const float4 wA = *(const float4*)&W2L[k*32 + og];
        const float4 wB = *(const float4*)&W2L[k*32 + og + 4];
        acc2[0] = fmaf(hv, wA.x, acc2[0]); acc2[1] = fmaf(hv, wA.y, acc2[1]);
        acc2[2] = fmaf(hv, wA.z, acc2[2]); acc2[3] = fmaf(hv, wA.w, acc2[3]);
        acc2[4] = fmaf(hv, wB.x, acc2[4]); acc2[5] = fmaf(hv, wB.y, acc2[5]);
        acc2[6] = fmaf(hv, wB.z, acc2[6]); acc2[7] = fmaf(hv, wB.w, acc2[7]);
    }
    float s = 0.f;
    #pragma unroll
    for (int j = 0; j < 8; j++) {
        const float g = acc2[j] / (1.f + __expf(-acc2[j]));
        s = fmaf(g, W3[og + j], s);
    }
    s += __shfl_xor(s, 1);
    s += __shfl_xor(s, 2);
    if ((tid & 3) == 0 && nb + nl < NN)
        atomicAdd(&gsum[batch[nb + nl]], s + b3[0]);
    __syncthreads();
    if (tid < 16) part[blockIdx.x * 16 + tid] = gsum[tid];
}

__global__ __launch_bounds__(64) void k_final(const float* __restrict__ part,
                                              float* __restrict__ out)
{
    const int t = threadIdx.x;
    if (t >= 16) return;
    float acc = 0.f;
    for (int b = 0; b < NBLK; b++) acc += part[b * 16 + t];
    out[t] = acc;
}

extern "C" void kernel_launch(void* const* d_in, const int* in_sizes, int n_in,
                              void* d_out, int out_size, void* d_ws, size_t ws_size,
                              hipStream_t stream)
{
    const float* pos    = (const float*)d_in[0];
    const int*   ntype  = (const int*)  d_in[1];
    const int*   src    = (const int*)  d_in[2];
    const int*   dst    = (const int*)  d_in[3];
    const float* shifts = (const float*)d_in[4];
    const int*   batch  = (const int*)  d_in[5];
    const float* Wemb   = (const float*)d_in[6];
    const float* freqs  = (const float*)d_in[7];
    const float* W_rt   = (const float*)d_in[8];
    const float* W_mem  = (const float*)d_in[9];
    const float* W_Ar   = (const float*)d_in[10];
    const float* W_chi  = (const float*)d_in[11];
    const float* W1     = (const float*)d_in[12];
    const float* b1     = (const float*)d_in[13];
    const float* W2     = (const float*)d_in[14];
    const float* b2     = (const float*)d_in[15];
    const float* W3     = (const float*)d_in[16];
    const float* b3     = (const float*)d_in[17];

    float*  ws    = (float*)d_ws;
    float*  A     = ws;                        // [NN,1080]
    float*  P1    = A    + (size_t)NN * 1080;  // [NN,64]
    float*  P2    = P1   + (size_t)NN * 64;    // [NN,64]
    float*  chi   = P2   + (size_t)NN * 64;    // [NN,9]
    float4* egeo  = (float4*)(chi + (size_t)NN * 9);       // [NE]
    int*    esrc  = (int*)(egeo + NE);                     // [NE]
    float*  ecode = (float*)(esrc + NE);                   // [NE,9]
    float*  part  = ecode + (size_t)NE * 9;                // [NBLK,16]
    int*    indeg  = (int*)(part + NBLK * 16);
    int*    offs   = indeg  + 10240;
    int*    cursor = offs   + 10240;

    hipMemsetAsync(indeg,  0, 10240 * sizeof(int), stream);
    hipMemsetAsync(cursor, 0, 10240 * sizeof(int), stream);

    k_hist<<<(NE + 255)/256, 256, 0, stream>>>(pos, src, dst, shifts, indeg);
    k_scan<<<1, 256, 0, stream>>>(indeg, offs);
    k_fill<<<(NE + 255)/256, 256, 0, stream>>>(pos, src, dst, shifts, ntype,
                                               Wemb, offs, cursor, esrc, egeo,
                                               ecode);
    k_node1<<<NN, 64, 0, stream>>>(freqs, W_rt, offs, indeg, esrc, egeo, ecode,
                                   W1, W_chi, A, chi, P1);
    k_node2<<<NN, 64, 0, stream>>>(freqs, W_rt, W_Ar, W_mem, offs, indeg, esrc,
                                   egeo, ecode, chi, A, W1, P2);
    k_tail<<<NBLK, 256, 0, stream>>>(P1, P2, b1, W2, b2, W3, b3, batch, part);
    k_final<<<1, 64, 0, stream>>>(part, (float*)d_out);
}

// Round 16
// 198.038 us; speedup vs baseline: 1.3702x; 1.0039x over previous
//
#include <hip/hip_runtime.h>
#include <hip/hip_bf16.h>
#include <math.h>

#define NE 80000
#define NN 10000
#define NG 16
#define NBLK 157   // ceil(NN/64)
#define MP_NORM 0.31622776601683794f   // 1/sqrt(10)
#define RBF_NORM 0.60302268915552724f  // sqrt(2/5.5)

// monomial tables: index -> (lx,ly,lz), l
__constant__ int c_mx[20] = {0, 1,0,0, 2,1,1,0,0,0, 3,2,2,1,1,1,0,0,0,0};
__constant__ int c_my[20] = {0, 0,1,0, 0,1,0,2,1,0, 0,1,0,2,1,0,3,2,1,0};
__constant__ int c_mz[20] = {0, 0,0,1, 0,0,1,0,1,2, 0,0,1,0,1,2,0,1,2,3};

__device__ __forceinline__ int l_of_a(int a) {
    return (a >= 10) ? 3 : ((a >= 4) ? 2 : ((a >= 1) ? 1 : 0));
}

// symmetrize one node's 1080-vector (in LDS, layout [s][a*9+c]) -> 324
// (single-wave use: writer lanes == reader wave, no barrier needed)
__device__ __forceinline__ void symm_from_lds(const float* Als, float* brow,
                                              int lane) {
    if (lane >= 54) return;
    const int s2 = lane / 9, c = lane - s2 * 9;
    const float* a = Als + s2 * 180 + c;
    float v[20];
    #pragma unroll
    for (int i = 0; i < 20; i++) v[i] = a[i * 9];
    const float o0 = v[0];
    const float o1 = v[1]*v[1] + v[2]*v[2] + v[3]*v[3];
    const float o2 = v[4]*v[4] + 2.f*v[5]*v[5] + 2.f*v[6]*v[6]
                   + v[7]*v[7] + 2.f*v[8]*v[8] + v[9]*v[9];
    const float o3 = v[10]*v[10] + 3.f*v[11]*v[11] + 3.f*v[12]*v[12]
                   + 3.f*v[13]*v[13] + 6.f*v[14]*v[14] + 3.f*v[15]*v[15]
                   + v[16]*v[16] + 3.f*v[17]*v[17] + 3.f*v[18]*v[18] + v[19]*v[19];
    const float o4 = v[1]*v[1]*v[4] + 2.f*v[1]*v[2]*v[5] + 2.f*v[1]*v[3]*v[6]
                   + 2.f*v[2]*v[1]*v[5] + v[2]*v[2]*v[7] + 2.f*v[2]*v[3]*v[8]
                   + 2.f*v[3]*v[1]*v[6] + 2.f*v[3]*v[2]*v[8] + v[3]*v[3]*v[9];
    const float o5 =
        v[1]*(v[4]*v[10] + 3.f*v[5]*v[11] + 3.f*v[6]*v[12] + 3.f*v[7]*v[13]
              + 6.f*v[8]*v[14] + 3.f*v[9]*v[15])
      + v[2]*(3.f*v[4]*v[11] + 3.f*v[5]*v[13] + 6.f*v[6]*v[14] + v[7]*v[16]
              + 3.f*v[8]*v[17] + 3.f*v[9]*v[18])
      + v[3]*(3.f*v[4]*v[12] + 6.f*v[5]*v[14] + 3.f*v[6]*v[15] + 3.f*v[7]*v[17]
              + 3.f*v[8]*v[18] + v[9]*v[19]);
    float* b = brow + s2 * 54 + c;
    b[0]  = o0;
    b[9]  = o1;
    b[18] = o2;
    b[27] = o3;
    b[36] = o4;
    b[45] = o5;
}

// ---------------------------------------------------------------------------
// CSR build: histogram, scan, fill (fill precomputes per-active-edge
// geometry, source node, and 9-element edge code).
// ---------------------------------------------------------------------------
__global__ __launch_bounds__(256) void k_hist(
    const float* __restrict__ pos, const int* __restrict__ src,
    const int* __restrict__ dst, const float* __restrict__ shifts,
    int* __restrict__ indeg)
{
    const int e = blockIdx.x * 256 + threadIdx.x;
    if (e >= NE) return;
    const int sn = src[e], dn = dst[e];
    const float vx = pos[3*dn+0] - pos[3*sn+0] + shifts[3*e+0];
    const float vy = pos[3*dn+1] - pos[3*sn+1] + shifts[3*e+1];
    const float vz = pos[3*dn+2] - pos[3*sn+2] + shifts[3*e+2];
    const float r = sqrtf(vx*vx + vy*vy + vz*vz) + 1e-9f;
    if (r * (1.0f / 5.5f) < 1.0f) atomicAdd(&indeg[dn], 1);
}

__global__ __launch_bounds__(256) void k_scan(const int* __restrict__ indeg,
                                              int* __restrict__ offs)
{
    __shared__ int part[256];
    const int t = threadIdx.x;
    int s = 0;
    for (int i = t * 40; i < t * 40 + 40; i++)
        if (i < NN) s += indeg[i];
    part[t] = s;
    __syncthreads();
    if (t == 0) {
        int run = 0;
        for (int i = 0; i < 256; i++) { int v = part[i]; part[i] = run; run += v; }
    }
    __syncthreads();
    int run = part[t];
    for (int i = t * 40; i < t * 40 + 40; i++) {
        if (i < NN) { offs[i] = run; run += indeg[i]; }
    }
}

__global__ __launch_bounds__(256) void k_fill(
    const float* __restrict__ pos, const int* __restrict__ src,
    const int* __restrict__ dst, const float* __restrict__ shifts,
    const int* __restrict__ ntype, const float* __restrict__ Wemb,
    const int* __restrict__ offs, int* __restrict__ cursor,
    int* __restrict__ esrc, float4* __restrict__ egeo,
    float* __restrict__ ecode)
{
    const int e = blockIdx.x * 256 + threadIdx.x;
    if (e >= NE) return;
    const int sn = src[e], dn = dst[e];
    const float vx = pos[3*dn+0] - pos[3*sn+0] + shifts[3*e+0];
    const float vy = pos[3*dn+1] - pos[3*sn+1] + shifts[3*e+1];
    const float vz = pos[3*dn+2] - pos[3*sn+2] + shifts[3*e+2];
    const float r = sqrtf(vx*vx + vy*vy + vz*vz) + 1e-9f;
    if (r * (1.0f / 5.5f) < 1.0f) {
        const int p = offs[dn] + atomicAdd(&cursor[dn], 1);
        esrc[p] = sn;
        const float inv = 1.0f / r;
        egeo[p] = make_float4(vx*inv, vy*inv, vz*inv, r);
        const int ts = ntype[sn], td = ntype[dn];
        const float es0 = Wemb[3*ts], es1 = Wemb[3*ts+1], es2 = Wemb[3*ts+2];
        const float ed0 = Wemb[3*td], ed1 = Wemb[3*td+1], ed2 = Wemb[3*td+2];
        float* cp = ecode + (size_t)p * 9;
        cp[0] = es0*ed0; cp[1] = es0*ed1; cp[2] = es0*ed2;
        cp[3] = es1*ed0; cp[4] = es1*ed1; cp[5] = es1*ed2;
        cp[6] = es2*ed0; cp[7] = es2*ed1; cp[8] = es2*ed2;
    }
}

// ---------------------------------------------------------------------------
// Pass 1: 128-thread blocks = 2 INDEPENDENT waves, wave w owns node
// 2*blockIdx+w (full r12 per-wave structure, own LDS slab, no barriers).
// ---------------------------------------------------------------------------
__global__ __launch_bounds__(128) void k_node1(
    const float* __restrict__ freqs, const float* __restrict__ W_rt,
    const int* __restrict__ offs, const int* __restrict__ indeg,
    const int* __restrict__ esrc, const float4* __restrict__ egeo,
    const float* __restrict__ ecode, const float* __restrict__ W1,
    const float* __restrict__ W_chi,
    float* __restrict__ A, float* __restrict__ chi, float* __restrict__ P1)
{
    __shared__ float AlsS[2][1080];
    __shared__ float BlsS[2][324];
    const int tid = threadIdx.x;
    const int lane = tid & 63, w = tid >> 6;
    const int n = blockIdx.x * 2 + w;
    float* Als = AlsS[w];
    float* Bls = BlsS[w];
    int aslot[3], cslot[3], rslot[3];
    float acc[3][6];
    #pragma unroll
    for (int j = 0; j < 3; j++) {
        const int p = lane + 64 * j;
        const int pc = (p < 180) ? p : 0;
        aslot[j] = pc / 9;
        cslot[j] = 20 + pc % 9;
        rslot[j] = 29 + 6 * l_of_a(pc / 9);
        #pragma unroll
        for (int s = 0; s < 6; s++) acc[j][s] = 0.f;
    }
    float fr[6];
    #pragma unroll
    for (int q = 0; q < 6; q++) fr[q] = freqs[q];
    float wrt[6];
    if (lane >= 29 && lane < 53) {
        const int j = lane - 29, l = j / 6, s2 = j % 6;
        #pragma unroll
        for (int q = 0; q < 6; q++) wrt[q] = W_rt[(l*6 + q)*6 + s2];
    }
    int mlx = 0, mly = 0, mlz = 0;
    if (lane < 20) { mlx = c_mx[lane]; mly = c_my[lane]; mlz = c_mz[lane]; }
    const int e0 = offs[n], cnt = indeg[n];
    float4 geo = make_float4(0.f, 0.f, 0.f, 1.f);
    float ecd = 0.f;
    if (cnt > 0) {
        geo = egeo[e0];
        if (lane >= 20 && lane < 29) ecd = ecode[(size_t)e0*9 + lane - 20];
    }
    for (int t = 0; t < cnt; t++) {
        const float4 g = geo;
        const float ec = ecd;
        if (t + 1 < cnt) {
            geo = egeo[e0 + t + 1];
            if (lane >= 20 && lane < 29)
                ecd = ecode[(size_t)(e0 + t + 1)*9 + lane - 20];
        }
        float regX = ec;
        if (lane < 20) {
            float v = 1.f;
            for (int i = 0; i < mlx; i++) v *= g.x;
            for (int i = 0; i < mly; i++) v *= g.y;
            for (int i = 0; i < mlz; i++) v *= g.z;
            regX = v;
        } else if (lane >= 29 && lane < 53) {
            const float r = g.w;
            const float u = r * (1.0f / 5.5f);
            const float u2 = u*u, u3 = u2*u, u6 = u3*u3;
            const float fcv = 1.0f - 28.0f*u6 + 48.0f*u6*u - 21.0f*u6*u2;
            const float inv = fcv / r;
            float s = 0.f;
            #pragma unroll
            for (int q = 0; q < 6; q++)
                s += RBF_NORM * __sinf(r * fr[q]) * inv * wrt[q];
            regX = s;
        }
        float pp[3];
        #pragma unroll
        for (int j = 0; j < 3; j++)
            pp[j] = __shfl(regX, aslot[j]) * __shfl(regX, cslot[j]);
        #pragma unroll
        for (int j = 0; j < 3; j++) {
            #pragma unroll
            for (int s = 0; s < 6; s++)
                acc[j][s] = fmaf(__shfl(regX, rslot[j] + s), pp[j], acc[j][s]);
        }
    }
    #pragma unroll
    for (int j = 0; j < 3; j++) {
        const int p = lane + 64 * j;
        if (p < 180) {
            #pragma unroll
            for (int s = 0; s < 6; s++) {
                A[(size_t)n*1080 + s*180 + p] = acc[j][s];
                Als[s*180 + p] = acc[j][s];
            }
        }
    }
    // same-wave LDS write->read: lgkmcnt ordering, no barrier
    symm_from_lds(Als, Bls, lane);
    // pipelined chi: group g=lane/9 covers j in [47g, min(324,47g+47))
    {
        float s = 0.f;
        if (lane < 63) {
            const int cc = lane % 9, gg = lane / 9;
            const int jb = gg * 47;
            const int je = (jb + 47 < 324) ? (jb + 47) : 324;
            float wc = W_chi[jb * 9 + cc];
            for (int j = jb; j < je; j++) {
                const float wn = (j + 1 < je) ? W_chi[(j + 1) * 9 + cc] : 0.f;
                s = fmaf(Bls[j], wc, s);
                wc = wn;
            }
        }
        float tt;
        tt = __shfl(s, lane + 36); if (lane < 27) s += tt;
        tt = __shfl(s, lane + 18); if (lane < 18) s += tt;
        tt = __shfl(s, lane + 9);
        if (lane < 9) chi[(size_t)n * 9 + lane] = s + tt;
    }
    // pipelined GEMV vs even W1 rows (324 = 54 x 6)
    {
        float cur[6], nxt[6];
        #pragma unroll
        for (int u = 0; u < 6; u++) cur[u] = W1[(size_t)(2*u)*64 + lane];
        float s0=0.f, s1=0.f, s2=0.f, s3=0.f, s4=0.f, s5=0.f;
        for (int q = 0; q < 324; q += 6) {
            const int qn = q + 6;
            if (qn < 324) {
                #pragma unroll
                for (int u = 0; u < 6; u++)
                    nxt[u] = W1[(size_t)(2*(qn+u))*64 + lane];
            }
            s0 = fmaf(Bls[q+0], cur[0], s0);
            s1 = fmaf(Bls[q+1], cur[1], s1);
            s2 = fmaf(Bls[q+2], cur[2], s2);
            s3 = fmaf(Bls[q+3], cur[3], s3);
            s4 = fmaf(Bls[q+4], cur[4], s4);
            s5 = fmaf(Bls[q+5], cur[5], s5);
            #pragma unroll
            for (int u = 0; u < 6; u++) cur[u] = nxt[u];
        }
        P1[(size_t)n*64 + lane] = ((s0 + s1) + (s2 + s3)) + (s4 + s5);
    }
}

// ---------------------------------------------------------------------------
// Pass 2: 2 independent waves per block, no barriers; memory term in place
// on the wave's own Als slab.
// ---------------------------------------------------------------------------
__global__ __launch_bounds__(128) void k_node2(
    const float* __restrict__ freqs, const float* __restrict__ W_rt,
    const float* __restrict__ W_Ar, const float* __restrict__ W_mem,
    const int* __restrict__ offs, const int* __restrict__ indeg,
    const int* __restrict__ esrc, const float4* __restrict__ egeo,
    const float* __restrict__ ecode, const float* __restrict__ chi,
    const float* __restrict__ A, const float* __restrict__ W1,
    float* __restrict__ P2)
{
    __shared__ float AlsS[2][1080];
    __shared__ float B2lsS[2][324];
    __shared__ float WmS[2][144];
    const int tid = threadIdx.x;
    const int lane = tid & 63, w = tid >> 6;
    const int n = blockIdx.x * 2 + w;
    float* Als  = AlsS[w];
    float* B2ls = B2lsS[w];
    float* Wm   = WmS[w];
    #pragma unroll
    for (int k = 0; k < 17; k++) {
        const int i = lane + 64 * k;
        if (i < 1080) Als[i] = A[(size_t)n*1080 + i];
    }
    Wm[lane] = W_mem[lane];
    Wm[lane + 64] = W_mem[lane + 64];
    if (lane < 16) Wm[lane + 128] = W_mem[lane + 128];
    int aslot[3], cslot[3], rslot[3];
    float acc[3][6];
    #pragma unroll
    for (int j = 0; j < 3; j++) {
        const int p = lane + 64 * j;
        const int pc = (p < 180) ? p : 0;
        aslot[j] = pc / 9;
        cslot[j] = 20 + pc % 9;
        rslot[j] = 29 + 6 * l_of_a(pc / 9);
        #pragma unroll
        for (int s = 0; s < 6; s++) acc[j][s] = 0.f;
    }
    float fr[6];
    #pragma unroll
    for (int q = 0; q < 6; q++) fr[q] = freqs[q];
    float wrtB[6], wrtA[6];
    if (lane >= 29 && lane < 53) {
        const int j = lane - 29, l = j / 6, s2 = j % 6;
        #pragma unroll
        for (int q = 0; q < 6; q++) {
            wrtB[q] = W_rt[(l*6 + q)*6 + s2];
            wrtA[q] = W_Ar[(l*6 + q)*6 + s2];
        }
    }
    int mlx = 0, mly = 0, mlz = 0;
    if (lane < 20) { mlx = c_mx[lane]; mly = c_my[lane]; mlz = c_mz[lane]; }
    const int e0 = offs[n], cnt = indeg[n];
    int sn2 = 0;
    float4 geo = make_float4(0.f, 0.f, 0.f, 1.f);
    float ecd = 0.f, chin = 0.f;
    float an[3][6];
    #pragma unroll
    for (int j = 0; j < 3; j++)
        #pragma unroll
        for (int s = 0; s < 6; s++) an[j][s] = 0.f;
    if (cnt > 0) {
        const int sn1 = esrc[e0];
        geo = egeo[e0];
        if (lane >= 20 && lane < 29) {
            ecd  = ecode[(size_t)e0*9 + lane - 20];
            chin = chi[(size_t)sn1*9 + lane - 20];
        }
        const float* ar = A + (size_t)sn1 * 1080;
        #pragma unroll
        for (int j = 0; j < 3; j++)
            #pragma unroll
            for (int s = 0; s < 6; s++) an[j][s] = ar[s*180 + lane + 64*j];
    }
    if (cnt > 1) sn2 = esrc[e0 + 1];
    for (int t = 0; t < cnt; t++) {
        const float4 g = geo;
        const float ec = ecd, ch = chin;
        float av[3][6];
        #pragma unroll
        for (int j = 0; j < 3; j++)
            #pragma unroll
            for (int s = 0; s < 6; s++) av[j][s] = an[j][s];
        if (t + 1 < cnt) {
            geo = egeo[e0 + t + 1];
            if (lane >= 20 && lane < 29) {
                ecd  = ecode[(size_t)(e0 + t + 1)*9 + lane - 20];
                chin = chi[(size_t)sn2*9 + lane - 20];
            }
            const float* ar = A + (size_t)sn2 * 1080;
            #pragma unroll
            for (int j = 0; j < 3; j++)
                #pragma unroll
                for (int s = 0; s < 6; s++) an[j][s] = ar[s*180 + lane + 64*j];
            if (t + 2 < cnt) sn2 = esrc[e0 + t + 2];
        }
        float regX = ec * ch;
        float regY = 0.f;
        if (lane < 20) {
            float v = 1.f;
            for (int i = 0; i < mlx; i++) v *= g.x;
            for (int i = 0; i < mly; i++) v *= g.y;
            for (int i = 0; i < mlz; i++) v *= g.z;
            regX = v;
        } else if (lane >= 29 && lane < 53) {
            const float r = g.w;
            const float u = r * (1.0f / 5.5f);
            const float u2 = u*u, u3 = u2*u, u6 = u3*u3;
            const float fcv = 1.0f - 28.0f*u6 + 48.0f*u6*u - 21.0f*u6*u2;
            const float inv = fcv / r;
            float sB = 0.f, sA = 0.f;
            #pragma unroll
            for (int q = 0; q < 6; q++) {
                const float rb = RBF_NORM * __sinf(r * fr[q]) * inv;
                sB = fmaf(rb, wrtB[q], sB);
                sA = fmaf(rb, wrtA[q], sA);
            }
            regX = sB;
            regY = sA;
        }
        float pp[3];
        #pragma unroll
        for (int j = 0; j < 3; j++)
            pp[j] = __shfl(regX, aslot[j]) * __shfl(regX, cslot[j]);
        #pragma unroll
        for (int j = 0; j < 3; j++) {
            #pragma unroll
            for (int s = 0; s < 6; s++) {
                const float rB = __shfl(regX, rslot[j] + s);
                const float rA = __shfl(regY, rslot[j] + s);
                acc[j][s] += rB * pp[j] + av[j][s] * rA;
            }
        }
    }
    // memory term + MP_NORM, IN PLACE on own Als slab (same-wave ordering)
    #pragma unroll
    for (int j = 0; j < 3; j++) {
        const int p = lane + 64 * j;
        if (p < 180) {
            const int l = l_of_a(p / 9);
            float als6[6];
            #pragma unroll
            for (int sp = 0; sp < 6; sp++) als6[sp] = Als[sp*180 + p];
            #pragma unroll
            for (int s = 0; s < 6; s++) {
                float m = 0.f;
                #pragma unroll
                for (int sp = 0; sp < 6; sp++)
                    m = fmaf(als6[sp], Wm[l*36 + sp*6 + s], m);
                Als[s*180 + p] = acc[j][s] * MP_NORM + m;
            }
        }
    }
    symm_from_lds(Als, B2ls, lane);
    // pipelined GEMV vs odd W1 rows
    {
        float cur[6], nxt[6];
        #pragma unroll
        for (int u = 0; u < 6; u++) cur[u] = W1[(size_t)(2*u + 1)*64 + lane];
        float s0=0.f, s1=0.f, s2=0.f, s3=0.f, s4=0.f, s5=0.f;
        for (int q = 0; q < 324; q += 6) {
            const int qn = q + 6;
            if (qn < 324) {
                #pragma unroll
                for (int u = 0; u < 6; u++)
                    nxt[u] = W1[(size_t)(2*(qn+u) + 1)*64 + lane];
            }
            s0 = fmaf(B2ls[q+0], cur[0], s0);
            s1 = fmaf(B2ls[q+1], cur[1], s1);
            s2 = fmaf(B2ls[q+2], cur[2], s2);
            s3 = fmaf(B2ls[q+3], cur[3], s3);
            s4 = fmaf(B2ls[q+4], cur[4], s4);
            s5 = fmaf(B2ls[q+5], cur[5], s5);
            #pragma unroll
            for (int u = 0; u < 6; u++) cur[u] = nxt[u];
        }
        P2[(size_t)n*64 + lane] = ((s0 + s1) + (s2 + s3)) + (s4 + s5);
    }
}

// ---------------------------------------------------------------------------
// Tail: 64 nodes per 256-thread block; LDS atomics only; block partials.
// ---------------------------------------------------------------------------
__global__ __launch_bounds__(256) void k_tail(
    const float* __restrict__ P1, const float* __restrict__ P2,
    const float* __restrict__ b1, const float* __restrict__ W2,
    const float* __restrict__ b2, const float* __restrict__ W3,
    const float* __restrict__ b3, const int* __restrict__ batch,
    float* __restrict__ part)
{
    __shared__ float h1s[64][66];
    __shared__ float W2L[2048];
    __shared__ float gsum[16];
    const int tid = threadIdx.x;
    const int nb = blockIdx.x * 64;
    if (tid < 16) gsum[tid] = 0.f;
    for (int idx = tid; idx < 2048; idx += 256) W2L[idx] = W2[idx];
    for (int idx = tid; idx < 4096; idx += 256) {
        const int nl = idx >> 6, o = idx & 63;
        float h = 0.f;
        if (nb + nl < NN)
            h = P1[(size_t)(nb + nl)*64 + o] + P2[(size_t)(nb + nl)*64 + o]
              + b1[o];
        h1s[nl][o] = h / (1.f + __expf(-h));
    }
    __syncthreads();
    const int nl = tid >> 2, og = (tid & 3) * 8;
    float acc2[8];
    #pragma unroll
    for (int j = 0; j < 8; j++) acc2[j] = b2[og + j];
    #pragma unroll 8
    for (int k = 0; k < 64; k++) {
        const float hv = h1s[nl][k];
        const float4 wA = *(const float4*)&W2L[k*32 + og];
        const float4 wB = *(const float4*)&W2L[k*32 + og + 4];
        acc2[0] = fmaf(hv, wA.x, acc2[0]); acc2[1] = fmaf(hv, wA.y, acc2[1]);
        acc2[2] = fmaf(hv, wA.z, acc2[2]); acc2[3] = fmaf(hv, wA.w, acc2[3]);
        acc2[4] = fmaf(hv, wB.x, acc2[4]); acc2[5] = fmaf(hv, wB.y, acc2[5]);
        acc2[6] = fmaf(hv, wB.z, acc2[6]); acc2[7] = fmaf(hv, wB.w, acc2[7]);
    }
    float s = 0.f;
    #pragma unroll
    for (int j = 0; j < 8; j++) {
        const float g = acc2[j] / (1.f + __expf(-acc2[j]));
        s = fmaf(g, W3[og + j], s);
    }
    s += __shfl_xor(s, 1);
    s += __shfl_xor(s, 2);
    if ((tid & 3) == 0 && nb + nl < NN)
        atomicAdd(&gsum[batch[nb + nl]], s + b3[0]);
    __syncthreads();
    if (tid < 16) part[blockIdx.x * 16 + tid] = gsum[tid];
}

__global__ __launch_bounds__(64) void k_final(const float* __restrict__ part,
                                              float* __restrict__ out)
{
    const int t = threadIdx.x;
    if (t >= 16) return;
    float acc = 0.f;
    for (int b = 0; b < NBLK; b++) acc += part[b * 16 + t];
    out[t] = acc;
}

extern "C" void kernel_launch(void* const* d_in, const int* in_sizes, int n_in,
                              void* d_out, int out_size, void* d_ws, size_t ws_size,
                              hipStream_t stream)
{
    const float* pos    = (const float*)d_in[0];
    const int*   ntype  = (const int*)  d_in[1];
    const int*   src    = (const int*)  d_in[2];
    const int*   dst    = (const int*)  d_in[3];
    const float* shifts = (const float*)d_in[4];
    const int*   batch  = (const int*)  d_in[5];
    const float* Wemb   = (const float*)d_in[6];
    const float* freqs  = (const float*)d_in[7];
    const float* W_rt   = (const float*)d_in[8];
    const float* W_mem  = (const float*)d_in[9];
    const float* W_Ar   = (const float*)d_in[10];
    const float* W_chi  = (const float*)d_in[11];
    const float* W1     = (const float*)d_in[12];
    const float* b1     = (const float*)d_in[13];
    const float* W2     = (const float*)d_in[14];
    const float* b2     = (const float*)d_in[15];
    const float* W3     = (const float*)d_in[16];
    const float* b3     = (const float*)d_in[17];

    float*  ws    = (float*)d_ws;
    float*  A     = ws;                        // [NN,1080]
    float*  P1    = A    + (size_t)NN * 1080;  // [NN,64]
    float*  P2    = P1   + (size_t)NN * 64;    // [NN,64]
    float*  chi   = P2   + (size_t)NN * 64;    // [NN,9]
    float4* egeo  = (float4*)(chi + (size_t)NN * 9);       // [NE]
    int*    esrc  = (int*)(egeo + NE);                     // [NE]
    float*  ecode = (float*)(esrc + NE);                   // [NE,9]
    float*  part  = ecode + (size_t)NE * 9;                // [NBLK,16]
    int*    indeg  = (int*)(part + NBLK * 16);
    int*    offs   = indeg  + 10240;
    int*    cursor = offs   + 10240;

    hipMemsetAsync(indeg,  0, 10240 * sizeof(int), stream);
    hipMemsetAsync(cursor, 0, 10240 * sizeof(int), stream);

    k_hist<<<(NE + 255)/256, 256, 0, stream>>>(pos, src, dst, shifts, indeg);
    k_scan<<<1, 256, 0, stream>>>(indeg, offs);
    k_fill<<<(NE + 255)/256, 256, 0, stream>>>(pos, src, dst, shifts, ntype,
                                               Wemb, offs, cursor, esrc, egeo,
                                               ecode);
    k_node1<<<NN/2, 128, 0, stream>>>(freqs, W_rt, offs, indeg, esrc, egeo,
                                      ecode, W1, W_chi, A, chi, P1);
    k_node2<<<NN/2, 128, 0, stream>>>(freqs, W_rt, W_Ar, W_mem, offs, indeg,
                                      esrc, egeo, ecode, chi, A, W1, P2);
    k_tail<<<NBLK, 256, 0, stream>>>(P1, P2, b1, W2, b2, W3, b3, batch, part);
    k_final<<<1, 64, 0, stream>>>(part, (float*)d_out);
}

// Round 17
// 173.411 us; speedup vs baseline: 1.5647x; 1.1420x over previous
//
#include <hip/hip_runtime.h>
#include <hip/hip_bf16.h>
#include <math.h>

#define NE 80000
#define NN 10000
#define NG 16
#define NBLK 157   // ceil(NN/64)
#define MP_NORM 0.31622776601683794f   // 1/sqrt(10)
#define RBF_NORM 0.60302268915552724f  // sqrt(2/5.5)

// monomial tables: index -> (lx,ly,lz), l
__constant__ int c_mx[20] = {0, 1,0,0, 2,1,1,0,0,0, 3,2,2,1,1,1,0,0,0,0};
__constant__ int c_my[20] = {0, 0,1,0, 0,1,0,2,1,0, 0,1,0,2,1,0,3,2,1,0};
__constant__ int c_mz[20] = {0, 0,0,1, 0,0,1,0,1,2, 0,0,1,0,1,2,0,1,2,3};

__device__ __forceinline__ int l_of_a(int a) {
    return (a >= 10) ? 3 : ((a >= 4) ? 2 : ((a >= 1) ? 1 : 0));
}

// symmetrize one node's 1080-vector (in LDS, layout [s][a*9+c]) -> 324
// (single-wave use: writer lanes == reader wave, no barrier needed)
__device__ __forceinline__ void symm_from_lds(const float* Als, float* brow,
                                              int lane) {
    if (lane >= 54) return;
    const int s2 = lane / 9, c = lane - s2 * 9;
    const float* a = Als + s2 * 180 + c;
    float v[20];
    #pragma unroll
    for (int i = 0; i < 20; i++) v[i] = a[i * 9];
    const float o0 = v[0];
    const float o1 = v[1]*v[1] + v[2]*v[2] + v[3]*v[3];
    const float o2 = v[4]*v[4] + 2.f*v[5]*v[5] + 2.f*v[6]*v[6]
                   + v[7]*v[7] + 2.f*v[8]*v[8] + v[9]*v[9];
    const float o3 = v[10]*v[10] + 3.f*v[11]*v[11] + 3.f*v[12]*v[12]
                   + 3.f*v[13]*v[13] + 6.f*v[14]*v[14] + 3.f*v[15]*v[15]
                   + v[16]*v[16] + 3.f*v[17]*v[17] + 3.f*v[18]*v[18] + v[19]*v[19];
    const float o4 = v[1]*v[1]*v[4] + 2.f*v[1]*v[2]*v[5] + 2.f*v[1]*v[3]*v[6]
                   + 2.f*v[2]*v[1]*v[5] + v[2]*v[2]*v[7] + 2.f*v[2]*v[3]*v[8]
                   + 2.f*v[3]*v[1]*v[6] + 2.f*v[3]*v[2]*v[8] + v[3]*v[3]*v[9];
    const float o5 =
        v[1]*(v[4]*v[10] + 3.f*v[5]*v[11] + 3.f*v[6]*v[12] + 3.f*v[7]*v[13]
              + 6.f*v[8]*v[14] + 3.f*v[9]*v[15])
      + v[2]*(3.f*v[4]*v[11] + 3.f*v[5]*v[13] + 6.f*v[6]*v[14] + v[7]*v[16]
              + 3.f*v[8]*v[17] + 3.f*v[9]*v[18])
      + v[3]*(3.f*v[4]*v[12] + 6.f*v[5]*v[14] + 3.f*v[6]*v[15] + 3.f*v[7]*v[17]
              + 3.f*v[8]*v[18] + v[9]*v[19]);
    float* b = brow + s2 * 54 + c;
    b[0]  = o0;
    b[9]  = o1;
    b[18] = o2;
    b[27] = o3;
    b[36] = o4;
    b[45] = o5;
}

// ---------------------------------------------------------------------------
// Pack: W1p[h][g][lane] = float4{W1[8g+2u+h][lane]}_{u=0..3}  (h=0 even,1 odd)
//       WchiT2[cc][j2]  = {W_chi[2j2][cc], W_chi[2j2+1][cc]}
// ---------------------------------------------------------------------------
__global__ __launch_bounds__(256) void k_pack(
    const float* __restrict__ W1, const float* __restrict__ W_chi,
    float4* __restrict__ W1p, float2* __restrict__ WchiT2)
{
    const int idx = blockIdx.x * 256 + threadIdx.x;
    if (idx < 2 * 81 * 64) {
        const int h = idx / (81 * 64);
        const int r = idx - h * 81 * 64;
        const int g = r >> 6, lane = r & 63;
        float4 v;
        v.x = W1[(size_t)(8*g + 0 + h)*64 + lane];
        v.y = W1[(size_t)(8*g + 2 + h)*64 + lane];
        v.z = W1[(size_t)(8*g + 4 + h)*64 + lane];
        v.w = W1[(size_t)(8*g + 6 + h)*64 + lane];
        W1p[idx] = v;
    } else if (idx < 2*81*64 + 9*162) {
        const int r = idx - 2*81*64;
        const int cc = r / 162, j2 = r - cc * 162;
        WchiT2[(size_t)cc*162 + j2] = make_float2(W_chi[(2*j2)*9 + cc],
                                                  W_chi[(2*j2 + 1)*9 + cc]);
    }
}

// ---------------------------------------------------------------------------
// CSR build: histogram, scan, fill (fill precomputes per-active-edge
// geometry, source node, and 9-element edge code).
// ---------------------------------------------------------------------------
__global__ __launch_bounds__(256) void k_hist(
    const float* __restrict__ pos, const int* __restrict__ src,
    const int* __restrict__ dst, const float* __restrict__ shifts,
    int* __restrict__ indeg)
{
    const int e = blockIdx.x * 256 + threadIdx.x;
    if (e >= NE) return;
    const int sn = src[e], dn = dst[e];
    const float vx = pos[3*dn+0] - pos[3*sn+0] + shifts[3*e+0];
    const float vy = pos[3*dn+1] - pos[3*sn+1] + shifts[3*e+1];
    const float vz = pos[3*dn+2] - pos[3*sn+2] + shifts[3*e+2];
    const float r = sqrtf(vx*vx + vy*vy + vz*vz) + 1e-9f;
    if (r * (1.0f / 5.5f) < 1.0f) atomicAdd(&indeg[dn], 1);
}

__global__ __launch_bounds__(256) void k_scan(const int* __restrict__ indeg,
                                              int* __restrict__ offs)
{
    __shared__ int part[256];
    const int t = threadIdx.x;
    int s = 0;
    for (int i = t * 40; i < t * 40 + 40; i++)
        if (i < NN) s += indeg[i];
    part[t] = s;
    __syncthreads();
    if (t == 0) {
        int run = 0;
        for (int i = 0; i < 256; i++) { int v = part[i]; part[i] = run; run += v; }
    }
    __syncthreads();
    int run = part[t];
    for (int i = t * 40; i < t * 40 + 40; i++) {
        if (i < NN) { offs[i] = run; run += indeg[i]; }
    }
}

__global__ __launch_bounds__(256) void k_fill(
    const float* __restrict__ pos, const int* __restrict__ src,
    const int* __restrict__ dst, const float* __restrict__ shifts,
    const int* __restrict__ ntype, const float* __restrict__ Wemb,
    const int* __restrict__ offs, int* __restrict__ cursor,
    int* __restrict__ esrc, float4* __restrict__ egeo,
    float* __restrict__ ecode)
{
    const int e = blockIdx.x * 256 + threadIdx.x;
    if (e >= NE) return;
    const int sn = src[e], dn = dst[e];
    const float vx = pos[3*dn+0] - pos[3*sn+0] + shifts[3*e+0];
    const float vy = pos[3*dn+1] - pos[3*sn+1] + shifts[3*e+1];
    const float vz = pos[3*dn+2] - pos[3*sn+2] + shifts[3*e+2];
    const float r = sqrtf(vx*vx + vy*vy + vz*vz) + 1e-9f;
    if (r * (1.0f / 5.5f) < 1.0f) {
        const int p = offs[dn] + atomicAdd(&cursor[dn], 1);
        esrc[p] = sn;
        const float inv = 1.0f / r;
        egeo[p] = make_float4(vx*inv, vy*inv, vz*inv, r);
        const int ts = ntype[sn], td = ntype[dn];
        const float es0 = Wemb[3*ts], es1 = Wemb[3*ts+1], es2 = Wemb[3*ts+2];
        const float ed0 = Wemb[3*td], ed1 = Wemb[3*td+1], ed2 = Wemb[3*td+2];
        float* cp = ecode + (size_t)p * 9;
        cp[0] = es0*ed0; cp[1] = es0*ed1; cp[2] = es0*ed2;
        cp[3] = es1*ed0; cp[4] = es1*ed1; cp[5] = es1*ed2;
        cp[6] = es2*ed0; cp[7] = es2*ed1; cp[8] = es2*ed2;
    }
}

// GEMV vs packed W1 (81 float4 loads, 3-deep rotation) -> out scalar per lane
__device__ __forceinline__ float gemv_packed(const float4* wp,
                                             const float* Bv, int lane) {
    float4 w0 = wp[(size_t)0*64 + lane];
    float4 w1 = wp[(size_t)1*64 + lane];
    float4 w2 = wp[(size_t)2*64 + lane];
    float s0 = 0.f, s1 = 0.f, s2 = 0.f, s3 = 0.f;
    for (int g = 0; g < 81; g += 3) {
        s0 = fmaf(Bv[4*g+ 0], w0.x, s0); s1 = fmaf(Bv[4*g+ 1], w0.y, s1);
        s2 = fmaf(Bv[4*g+ 2], w0.z, s2); s3 = fmaf(Bv[4*g+ 3], w0.w, s3);
        if (g + 3 < 81) w0 = wp[(size_t)(g+3)*64 + lane];
        s0 = fmaf(Bv[4*g+ 4], w1.x, s0); s1 = fmaf(Bv[4*g+ 5], w1.y, s1);
        s2 = fmaf(Bv[4*g+ 6], w1.z, s2); s3 = fmaf(Bv[4*g+ 7], w1.w, s3);
        if (g + 4 < 81) w1 = wp[(size_t)(g+4)*64 + lane];
        s0 = fmaf(Bv[4*g+ 8], w2.x, s0); s1 = fmaf(Bv[4*g+ 9], w2.y, s1);
        s2 = fmaf(Bv[4*g+10], w2.z, s2); s3 = fmaf(Bv[4*g+11], w2.w, s3);
        if (g + 5 < 81) w2 = wp[(size_t)(g+5)*64 + lane];
    }
    return (s0 + s1) + (s2 + s3);
}

// ---------------------------------------------------------------------------
// Pass 1: 128-thread blocks = 2 INDEPENDENT waves, wave w owns node
// 2*blockIdx+w (own LDS slab, no barriers). Packed GEMV + packed chi.
// ---------------------------------------------------------------------------
__global__ __launch_bounds__(128) void k_node1(
    const float* __restrict__ freqs, const float* __restrict__ W_rt,
    const int* __restrict__ offs, const int* __restrict__ indeg,
    const int* __restrict__ esrc, const float4* __restrict__ egeo,
    const float* __restrict__ ecode, const float4* __restrict__ W1p,
    const float2* __restrict__ WchiT2,
    float* __restrict__ A, float* __restrict__ chi, float* __restrict__ P1)
{
    __shared__ float AlsS[2][1080];
    __shared__ float BlsS[2][324];
    const int tid = threadIdx.x;
    const int lane = tid & 63, w = tid >> 6;
    const int n = blockIdx.x * 2 + w;
    float* Als = AlsS[w];
    float* Bls = BlsS[w];
    int aslot[3], cslot[3], rslot[3];
    float acc[3][6];
    #pragma unroll
    for (int j = 0; j < 3; j++) {
        const int p = lane + 64 * j;
        const int pc = (p < 180) ? p : 0;
        aslot[j] = pc / 9;
        cslot[j] = 20 + pc % 9;
        rslot[j] = 29 + 6 * l_of_a(pc / 9);
        #pragma unroll
        for (int s = 0; s < 6; s++) acc[j][s] = 0.f;
    }
    float fr[6];
    #pragma unroll
    for (int q = 0; q < 6; q++) fr[q] = freqs[q];
    float wrt[6];
    if (lane >= 29 && lane < 53) {
        const int j = lane - 29, l = j / 6, s2 = j % 6;
        #pragma unroll
        for (int q = 0; q < 6; q++) wrt[q] = W_rt[(l*6 + q)*6 + s2];
    }
    int mlx = 0, mly = 0, mlz = 0;
    if (lane < 20) { mlx = c_mx[lane]; mly = c_my[lane]; mlz = c_mz[lane]; }
    const int e0 = offs[n], cnt = indeg[n];
    float4 geo = make_float4(0.f, 0.f, 0.f, 1.f);
    float ecd = 0.f;
    if (cnt > 0) {
        geo = egeo[e0];
        if (lane >= 20 && lane < 29) ecd = ecode[(size_t)e0*9 + lane - 20];
    }
    for (int t = 0; t < cnt; t++) {
        const float4 g = geo;
        const float ec = ecd;
        if (t + 1 < cnt) {
            geo = egeo[e0 + t + 1];
            if (lane >= 20 && lane < 29)
                ecd = ecode[(size_t)(e0 + t + 1)*9 + lane - 20];
        }
        float regX = ec;
        if (lane < 20) {
            float v = 1.f;
            for (int i = 0; i < mlx; i++) v *= g.x;
            for (int i = 0; i < mly; i++) v *= g.y;
            for (int i = 0; i < mlz; i++) v *= g.z;
            regX = v;
        } else if (lane >= 29 && lane < 53) {
            const float r = g.w;
            const float u = r * (1.0f / 5.5f);
            const float u2 = u*u, u3 = u2*u, u6 = u3*u3;
            const float fcv = 1.0f - 28.0f*u6 + 48.0f*u6*u - 21.0f*u6*u2;
            const float inv = fcv / r;
            float s = 0.f;
            #pragma unroll
            for (int q = 0; q < 6; q++)
                s += RBF_NORM * __sinf(r * fr[q]) * inv * wrt[q];
            regX = s;
        }
        float pp[3];
        #pragma unroll
        for (int j = 0; j < 3; j++)
            pp[j] = __shfl(regX, aslot[j]) * __shfl(regX, cslot[j]);
        #pragma unroll
        for (int j = 0; j < 3; j++) {
            #pragma unroll
            for (int s = 0; s < 6; s++)
                acc[j][s] = fmaf(__shfl(regX, rslot[j] + s), pp[j], acc[j][s]);
        }
    }
    #pragma unroll
    for (int j = 0; j < 3; j++) {
        const int p = lane + 64 * j;
        if (p < 180) {
            #pragma unroll
            for (int s = 0; s < 6; s++) {
                A[(size_t)n*1080 + s*180 + p] = acc[j][s];
                Als[s*180 + p] = acc[j][s];
            }
        }
    }
    // same-wave LDS write->read: lgkmcnt ordering, no barrier
    symm_from_lds(Als, Bls, lane);
    // packed chi: 54 lanes, 6 groups of 54 j's, 27 float2 loads (2-deep)
    {
        float s = 0.f;
        if (lane < 54) {
            const int cc = lane % 9, gg = lane / 9;
            const float2* wc = WchiT2 + (size_t)cc * 162 + gg * 27;
            const int jb = gg * 54;
            float2 c0 = wc[0];
            float2 c1 = wc[1];
            for (int i = 0; i < 27; i += 2) {
                s = fmaf(Bls[jb + 2*i    ], c0.x, s);
                s = fmaf(Bls[jb + 2*i + 1], c0.y, s);
                if (i + 2 < 27) c0 = wc[i + 2];
                if (i + 1 < 27) {
                    s = fmaf(Bls[jb + 2*i + 2], c1.x, s);
                    s = fmaf(Bls[jb + 2*i + 3], c1.y, s);
                    if (i + 3 < 27) c1 = wc[i + 3];
                }
            }
        }
        const float t1 = __shfl(s, lane + 27);
        if (lane < 27) s += t1;
        const float t2 = __shfl(s, lane + 9);
        const float t3 = __shfl(s, lane + 18);
        if (lane < 9) chi[(size_t)n * 9 + lane] = s + t2 + t3;
    }
    // packed GEMV vs even W1 rows
    P1[(size_t)n*64 + lane] = gemv_packed(W1p, Bls, lane);
}

// ---------------------------------------------------------------------------
// Pass 2: 2 independent waves per block, no barriers; memory term in place
// on the wave's own Als slab; packed GEMV (odd rows).
// ---------------------------------------------------------------------------
__global__ __launch_bounds__(128) void k_node2(
    const float* __restrict__ freqs, const float* __restrict__ W_rt,
    const float* __restrict__ W_Ar, const float* __restrict__ W_mem,
    const int* __restrict__ offs, const int* __restrict__ indeg,
    const int* __restrict__ esrc, const float4* __restrict__ egeo,
    const float* __restrict__ ecode, const float* __restrict__ chi,
    const float* __restrict__ A, const float4* __restrict__ W1p,
    float* __restrict__ P2)
{
    __shared__ float AlsS[2][1080];
    __shared__ float B2lsS[2][324];
    __shared__ float WmS[2][144];
    const int tid = threadIdx.x;
    const int lane = tid & 63, w = tid >> 6;
    const int n = blockIdx.x * 2 + w;
    float* Als  = AlsS[w];
    float* B2ls = B2lsS[w];
    float* Wm   = WmS[w];
    #pragma unroll
    for (int k = 0; k < 17; k++) {
        const int i = lane + 64 * k;
        if (i < 1080) Als[i] = A[(size_t)n*1080 + i];
    }
    Wm[lane] = W_mem[lane];
    Wm[lane + 64] = W_mem[lane + 64];
    if (lane < 16) Wm[lane + 128] = W_mem[lane + 128];
    int aslot[3], cslot[3], rslot[3];
    float acc[3][6];
    #pragma unroll
    for (int j = 0; j < 3; j++) {
        const int p = lane + 64 * j;
        const int pc = (p < 180) ? p : 0;
        aslot[j] = pc / 9;
        cslot[j] = 20 + pc % 9;
        rslot[j] = 29 + 6 * l_of_a(pc / 9);
        #pragma unroll
        for (int s = 0; s < 6; s++) acc[j][s] = 0.f;
    }
    float fr[6];
    #pragma unroll
    for (int q = 0; q < 6; q++) fr[q] = freqs[q];
    float wrtB[6], wrtA[6];
    if (lane >= 29 && lane < 53) {
        const int j = lane - 29, l = j / 6, s2 = j % 6;
        #pragma unroll
        for (int q = 0; q < 6; q++) {
            wrtB[q] = W_rt[(l*6 + q)*6 + s2];
            wrtA[q] = W_Ar[(l*6 + q)*6 + s2];
        }
    }
    int mlx = 0, mly = 0, mlz = 0;
    if (lane < 20) { mlx = c_mx[lane]; mly = c_my[lane]; mlz = c_mz[lane]; }
    const int e0 = offs[n], cnt = indeg[n];
    int sn2 = 0;
    float4 geo = make_float4(0.f, 0.f, 0.f, 1.f);
    float ecd = 0.f, chin = 0.f;
    float an[3][6];
    #pragma unroll
    for (int j = 0; j < 3; j++)
        #pragma unroll
        for (int s = 0; s < 6; s++) an[j][s] = 0.f;
    if (cnt > 0) {
        const int sn1 = esrc[e0];
        geo = egeo[e0];
        if (lane >= 20 && lane < 29) {
            ecd  = ecode[(size_t)e0*9 + lane - 20];
            chin = chi[(size_t)sn1*9 + lane - 20];
        }
        const float* ar = A + (size_t)sn1 * 1080;
        #pragma unroll
        for (int j = 0; j < 3; j++)
            #pragma unroll
            for (int s = 0; s < 6; s++) an[j][s] = ar[s*180 + lane + 64*j];
    }
    if (cnt > 1) sn2 = esrc[e0 + 1];
    for (int t = 0; t < cnt; t++) {
        const float4 g = geo;
        const float ec = ecd, ch = chin;
        float av[3][6];
        #pragma unroll
        for (int j = 0; j < 3; j++)
            #pragma unroll
            for (int s = 0; s < 6; s++) av[j][s] = an[j][s];
        if (t + 1 < cnt) {
            geo = egeo[e0 + t + 1];
            if (lane >= 20 && lane < 29) {
                ecd  = ecode[(size_t)(e0 + t + 1)*9 + lane - 20];
                chin = chi[(size_t)sn2*9 + lane - 20];
            }
            const float* ar = A + (size_t)sn2 * 1080;
            #pragma unroll
            for (int j = 0; j < 3; j++)
                #pragma unroll
                for (int s = 0; s < 6; s++) an[j][s] = ar[s*180 + lane + 64*j];
            if (t + 2 < cnt) sn2 = esrc[e0 + t + 2];
        }
        float regX = ec * ch;
        float regY = 0.f;
        if (lane < 20) {
            float v = 1.f;
            for (int i = 0; i < mlx; i++) v *= g.x;
            for (int i = 0; i < mly; i++) v *= g.y;
            for (int i = 0; i < mlz; i++) v *= g.z;
            regX = v;
        } else if (lane >= 29 && lane < 53) {
            const float r = g.w;
            const float u = r * (1.0f / 5.5f);
            const float u2 = u*u, u3 = u2*u, u6 = u3*u3;
            const float fcv = 1.0f - 28.0f*u6 + 48.0f*u6*u - 21.0f*u6*u2;
            const float inv = fcv / r;
            float sB = 0.f, sA = 0.f;
            #pragma unroll
            for (int q = 0; q < 6; q++) {
                const float rb = RBF_NORM * __sinf(r * fr[q]) * inv;
                sB = fmaf(rb, wrtB[q], sB);
                sA = fmaf(rb, wrtA[q], sA);
            }
            regX = sB;
            regY = sA;
        }
        float pp[3];
        #pragma unroll
        for (int j = 0; j < 3; j++)
            pp[j] = __shfl(regX, aslot[j]) * __shfl(regX, cslot[j]);
        #pragma unroll
        for (int j = 0; j < 3; j++) {
            #pragma unroll
            for (int s = 0; s < 6; s++) {
                const float rB = __shfl(regX, rslot[j] + s);
                const float rA = __shfl(regY, rslot[j] + s);
                acc[j][s] += rB * pp[j] + av[j][s] * rA;
            }
        }
    }
    // memory term + MP_NORM, IN PLACE on own Als slab (same-wave ordering)
    #pragma unroll
    for (int j = 0; j < 3; j++) {
        const int p = lane + 64 * j;
        if (p < 180) {
            const int l = l_of_a(p / 9);
            float als6[6];
            #pragma unroll
            for (int sp = 0; sp < 6; sp++) als6[sp] = Als[sp*180 + p];
            #pragma unroll
            for (int s = 0; s < 6; s++) {
                float m = 0.f;
                #pragma unroll
                for (int sp = 0; sp < 6; sp++)
                    m = fmaf(als6[sp], Wm[l*36 + sp*6 + s], m);
                Als[s*180 + p] = acc[j][s] * MP_NORM + m;
            }
        }
    }
    symm_from_lds(Als, B2ls, lane);
    // packed GEMV vs odd W1 rows
    P2[(size_t)n*64 + lane] = gemv_packed(W1p + (size_t)81*64, B2ls, lane);
}

// ---------------------------------------------------------------------------
// Tail: 64 nodes per 256-thread block; LDS atomics only; block partials.
// ---------------------------------------------------------------------------
__global__ __launch_bounds__(256) void k_tail(
    const float* __restrict__ P1, const float* __restrict__ P2,
    const float* __restrict__ b1, const float* __restrict__ W2,
    const float* __restrict__ b2, const float* __restrict__ W3,
    const float* __restrict__ b3, const int* __restrict__ batch,
    float* __restrict__ part)
{
    __shared__ float h1s[64][66];
    __shared__ float W2L[2048];
    __shared__ float gsum[16];
    const int tid = threadIdx.x;
    const int nb = blockIdx.x * 64;
    if (tid < 16) gsum[tid] = 0.f;
    for (int idx = tid; idx < 2048; idx += 256) W2L[idx] = W2[idx];
    for (int idx = tid; idx < 4096; idx += 256) {
        const int nl = idx >> 6, o = idx & 63;
        float h = 0.f;
        if (nb + nl < NN)
            h = P1[(size_t)(nb + nl)*64 + o] + P2[(size_t)(nb + nl)*64 + o]
              + b1[o];
        h1s[nl][o] = h / (1.f + __expf(-h));
    }
    __syncthreads();
    const int nl = tid >> 2, og = (tid & 3) * 8;
    float acc2[8];
    #pragma unroll
    for (int j = 0; j < 8; j++) acc2[j] = b2[og + j];
    #pragma unroll 8
    for (int k = 0; k < 64; k++) {
        const float hv = h1s[nl][k];
        const float4 wA = *(const float4*)&W2L[k*32 + og];
        const float4 wB = *(const float4*)&W2L[k*32 + og + 4];
        acc2[0] = fmaf(hv, wA.x, acc2[0]); acc2[1] = fmaf(hv, wA.y, acc2[1]);
        acc2[2] = fmaf(hv, wA.z, acc2[2]); acc2[3] = fmaf(hv, wA.w, acc2[3]);
        acc2[4] = fmaf(hv, wB.x, acc2[4]); acc2[5] = fmaf(hv, wB.y, acc2[5]);
        acc2[6] = fmaf(hv, wB.z, acc2[6]); acc2[7] = fmaf(hv, wB.w, acc2[7]);
    }
    float s = 0.f;
    #pragma unroll
    for (int j = 0; j < 8; j++) {
        const float g = acc2[j] / (1.f + __expf(-acc2[j]));
        s = fmaf(g, W3[og + j], s);
    }
    s += __shfl_xor(s, 1);
    s += __shfl_xor(s, 2);
    if ((tid & 3) == 0 && nb + nl < NN)
        atomicAdd(&gsum[batch[nb + nl]], s + b3[0]);
    __syncthreads();
    if (tid < 16) part[blockIdx.x * 16 + tid] = gsum[tid];
}

__global__ __launch_bounds__(64) void k_final(const float* __restrict__ part,
                                              float* __restrict__ out)
{
    const int t = threadIdx.x;
    if (t >= 16) return;
    float acc = 0.f;
    for (int b = 0; b < NBLK; b++) acc += part[b * 16 + t];
    out[t] = acc;
}

extern "C" void kernel_launch(void* const* d_in, const int* in_sizes, int n_in,
                              void* d_out, int out_size, void* d_ws, size_t ws_size,
                              hipStream_t stream)
{
    const float* pos    = (const float*)d_in[0];
    const int*   ntype  = (const int*)  d_in[1];
    const int*   src    = (const int*)  d_in[2];
    const int*   dst    = (const int*)  d_in[3];
    const float* shifts = (const float*)d_in[4];
    const int*   batch  = (const int*)  d_in[5];
    const float* Wemb   = (const float*)d_in[6];
    const float* freqs  = (const float*)d_in[7];
    const float* W_rt   = (const float*)d_in[8];
    const float* W_mem  = (const float*)d_in[9];
    const float* W_Ar   = (const float*)d_in[10];
    const float* W_chi  = (const float*)d_in[11];
    const float* W1     = (const float*)d_in[12];
    const float* b1     = (const float*)d_in[13];
    const float* W2     = (const float*)d_in[14];
    const float* b2     = (const float*)d_in[15];
    const float* W3     = (const float*)d_in[16];
    const float* b3     = (const float*)d_in[17];

    float*  ws    = (float*)d_ws;
    float*  A     = ws;                        // [NN,1080]
    float*  P1    = A    + (size_t)NN * 1080;  // [NN,64]
    float*  P2    = P1   + (size_t)NN * 64;    // [NN,64]
    float*  chi   = P2   + (size_t)NN * 64;    // [NN,9]
    float4* egeo  = (float4*)(chi + (size_t)NN * 9);       // [NE]
    int*    esrc  = (int*)(egeo + NE);                     // [NE]
    float*  ecode = (float*)(esrc + NE);                   // [NE,9]
    float*  part  = ecode + (size_t)NE * 9;                // [NBLK,16]
    int*    indeg  = (int*)(part + NBLK * 16);
    int*    offs   = indeg  + 10240;
    int*    cursor = offs   + 10240;
    float4* W1p    = (float4*)(cursor + 10240);            // [2*81*64]
    float2* WchiT2 = (float2*)(W1p + 2*81*64);             // [9*162]

    hipMemsetAsync(indeg,  0, 10240 * sizeof(int), stream);
    hipMemsetAsync(cursor, 0, 10240 * sizeof(int), stream);

    k_pack<<<48, 256, 0, stream>>>(W1, W_chi, W1p, WchiT2);
    k_hist<<<(NE + 255)/256, 256, 0, stream>>>(pos, src, dst, shifts, indeg);
    k_scan<<<1, 256, 0, stream>>>(indeg, offs);
    k_fill<<<(NE + 255)/256, 256, 0, stream>>>(pos, src, dst, shifts, ntype,
                                               Wemb, offs, cursor, esrc, egeo,
                                               ecode);
    k_node1<<<NN/2, 128, 0, stream>>>(freqs, W_rt, offs, indeg, esrc, egeo,
                                      ecode, W1p, WchiT2, A, chi, P1);
    k_node2<<<NN/2, 128, 0, stream>>>(freqs, W_rt, W_Ar, W_mem, offs, indeg,
                                      esrc, egeo, ecode, chi, A, W1p, P2);
    k_tail<<<NBLK, 256, 0, stream>>>(P1, P2, b1, W2, b2, W3, b3, batch, part);
    k_final<<<1, 64, 0, stream>>>(part, (float*)d_out);
}